// Round 3
// baseline (388.825 us; speedup 1.0000x reference)
//
#include <hip/hip_runtime.h>

#define NROWS 4096
#define DDIM  128
#define NHEAD 8
#define LOG2E 1.44269504088896f

// native 2^x  ->  single v_exp_f32 (ocml symbol always present in device libs)
extern "C" __device__ float __ocml_native_exp2_f32(float);

typedef __attribute__((ext_vector_type(8))) short    short8;
typedef __attribute__((ext_vector_type(8))) _Float16 half8;
typedef __attribute__((ext_vector_type(4))) float    floatx4;

__device__ __forceinline__ float bf2f(unsigned short u){
  unsigned v = ((unsigned)u) << 16;
  return __builtin_bit_cast(float, v);
}
__device__ __forceinline__ unsigned short f2bf(float f){
  unsigned u = __builtin_bit_cast(unsigned, f);
  u += 0x7FFFu + ((u >> 16) & 1u);
  return (unsigned short)(u >> 16);
}
__device__ __forceinline__ void split2(float v, unsigned short& hi, unsigned short& lo){
  hi = f2bf(v);
  lo = f2bf(v - bf2f(hi));
}
// async global->LDS, 16B per lane: LDS dest = wave-uniform base + lane*16.
__device__ __forceinline__ void async_cp16(const _Float16* g, _Float16* l){
  __builtin_amdgcn_global_load_lds(
      (const __attribute__((address_space(1))) void*)g,
      (__attribute__((address_space(3))) void*)l, 16, 0, 0);
}

// fp32 sentinels: 500=ws too small, 1000=in_sizes mismatch, 2000=launch fail.
__global__ void fill_kernel(float* __restrict__ out, float val, int n){
  int i = blockIdx.x * 256 + threadIdx.x;
  if (i < n) out[i] = val;
}

// ---------------------------------------------------------------------------
// Kernel 1: k = x@Wk[h], v = x@Wv[h], q = x@Wq[h]*log2e.
// k/v: fp16 outputs in MFMA fragment order with bank swizzle
//   qX = quad ^ ((l4>>1)&3) baked in.  q: plain row-major fp16 (which IS the
//   16x16x32 A-frag load order), pre-scaled by log2(e) for base-2 softmax.
// 3-term bf16 MFMA. grid (16, NHEAD, 3): four 64-row tiles per block,
// W staged once per half with COALESCED loads (lanes walk the d axis).
// ---------------------------------------------------------------------------
__global__ __launch_bounds__(256, 2) void proj_kernel(
    const float* __restrict__ x,
    const float* __restrict__ Wk, const float* __restrict__ Wv,
    const float* __restrict__ Wq,
    _Float16* __restrict__ kfo, _Float16* __restrict__ vfo,
    _Float16* __restrict__ qfo)
{
  __shared__ alignas(16) unsigned short wthi[DDIM][72];
  __shared__ alignas(16) unsigned short wtlo[DDIM][72];
  const int tid = threadIdx.x, lane = tid & 63, wave = tid >> 6;
  const int l4 = lane & 15, quad = lane >> 4;
  const int h = blockIdx.y, z = blockIdx.z;
  const float* W = (z == 0 ? Wk : (z == 1 ? Wv : Wq)) + h * DDIM * DDIM;

  floatx4 acc[4][8];
#pragma unroll
  for (int t4 = 0; t4 < 4; t4++)
#pragma unroll
    for (int c = 0; c < 8; c++) acc[t4][c] = (floatx4)0.f;

  for (int fh = 0; fh < 2; fh++) {
    // coalesced: consecutive lanes read consecutive d (4B stride)
    for (int i = tid; i < DDIM * 64; i += 256) {
      const int d = i & 127, fl = i >> 7;
      unsigned short hi, lo;
      split2(W[(fh * 64 + fl) * DDIM + d], hi, lo);
      wthi[d][fl] = hi; wtlo[d][fl] = lo;
    }
    __syncthreads();

#pragma unroll
    for (int t4 = 0; t4 < 4; t4++) {
      const int tile = blockIdx.x * 4 + t4;
      const float* xr = x + (size_t)(tile * 64 + wave * 16 + l4) * DDIM + fh * 64 + quad * 8;
      short8 ah[2], al[2];
#pragma unroll
      for (int t2 = 0; t2 < 2; t2++) {
        float4 v0 = *(const float4*)(xr + t2 * 32);
        float4 v1 = *(const float4*)(xr + t2 * 32 + 4);
        float xv[8] = {v0.x, v0.y, v0.z, v0.w, v1.x, v1.y, v1.z, v1.w};
#pragma unroll
        for (int j = 0; j < 8; j++) {
          unsigned short hi, lo; split2(xv[j], hi, lo);
          ah[t2][j] = (short)hi; al[t2][j] = (short)lo;
        }
      }
#pragma unroll
      for (int t2 = 0; t2 < 2; t2++) {
#pragma unroll
        for (int c = 0; c < 8; c++) {
          short8 bh = *(const short8*)(&wthi[c * 16 + l4][t2 * 32 + quad * 8]);
          short8 bl = *(const short8*)(&wtlo[c * 16 + l4][t2 * 32 + quad * 8]);
          acc[t4][c] = __builtin_amdgcn_mfma_f32_16x16x32_bf16(ah[t2], bh, acc[t4][c], 0, 0, 0);
          acc[t4][c] = __builtin_amdgcn_mfma_f32_16x16x32_bf16(al[t2], bh, acc[t4][c], 0, 0, 0);
          acc[t4][c] = __builtin_amdgcn_mfma_f32_16x16x32_bf16(ah[t2], bl, acc[t4][c], 0, 0, 0);
        }
      }
    }
    __syncthreads();
  }

  const int rb = wave * 16 + quad * 4;
#pragma unroll
  for (int t4 = 0; t4 < 4; t4++) {
    const int tile = blockIdx.x * 4 + t4;
    const size_t tilebase = (size_t)(h * 64 + tile) * 8192;
#pragma unroll
    for (int c = 0; c < 8; c++) {
      const int d = c * 16 + l4;
#pragma unroll
      for (int r = 0; r < 4; r++) {
        const int kl = rb + r;
        const float val = acc[t4][c][r];
        if (z == 0) {
          const int c2 = kl >> 4, l4k = kl & 15;
          const int tt = d >> 5, qd = (d >> 3) & 3, jj = d & 7;
          const int qX = qd ^ ((l4k >> 1) & 3);
          kfo[tilebase + (size_t)((c2 * 4 + tt) * 16 + l4k) * 32 + qX * 8 + jj] =
              (_Float16)val;
        } else if (z == 1) {
          const int c2 = d >> 4, l4v = d & 15;
          const int tt = kl >> 5, qd = (kl >> 3) & 3, jj = kl & 7;
          const int qX = qd ^ ((l4v >> 1) & 3);
          vfo[tilebase + (size_t)((c2 * 2 + tt) * 16 + l4v) * 32 + qX * 8 + jj] =
              (_Float16)val;
        } else {
          // q: row-major fp16, scaled by log2(e) for base-2 softmax
          qfo[((size_t)h * NROWS + (size_t)tile * 64 + kl) * DDIM + d] =
              (_Float16)(val * LOG2E);
        }
      }
    }
  }
}

// ---------------------------------------------------------------------------
// Kernel 2: flash attention. 64 q-rows/block (1 row-group/wave), SPLIT-K x2.
// grid 1024: h=bid&7 (XCD-affine), qt=(bid>>3)&63, s=bid>>9.
// Q A-frags loaded directly from qfo (row-major fp16 == frag order).
// LDS 40960 B * 4 = 163840 B = exactly the CU's LDS -> 4 blocks/CU, and
// grid 1024 = 4 * 256 CUs exactly: full residency, NO drain tail.
// __launch_bounds__(256,4): round-2 measured VGPR=80 (V-loads placed after
// P-store keep the live set small), so the 128-reg cap does NOT spill now
// (round-1 spill was the early-V-load live-range, since fixed).
// P LDS tile XOR-swizzled: byte ^= ((row>>3)&3)<<5 on store AND read —
// kills the 8-way ds_write_b16 conflict (was 2^22 conflict cycles exactly).
// s_setprio(1) around MFMA clusters: 4 independent blocks/CU give the
// phase diversity that makes the hint pay (m191 regime).
// Softmax in base-2 (Q pre-scaled): native v_exp_f32, no mul.
// ---------------------------------------------------------------------------
struct FlashLds {
  _Float16 k[2][8192];  // 32768 B
  _Float16 p[4][1024];  // 8192 B, wave-private P tile [kblk8][qrow16][8], swz
};

__global__ __launch_bounds__(256, 4) void flash_kernel(
    const _Float16* __restrict__ qfo, const _Float16* __restrict__ kfo,
    const _Float16* __restrict__ vfo,
    _Float16* __restrict__ op, float* __restrict__ mb, float* __restrict__ lb)
{
  __shared__ alignas(16) FlashLds lds;
  const int tid = threadIdx.x, lane = tid & 63, wave = tid >> 6;
  const int l4 = lane & 15, quad = lane >> 4;
  const int h = blockIdx.x & 7, qt = (blockIdx.x >> 3) & 63, s = blockIdx.x >> 9;
  const int q0 = qt * 64;

  // Q A-frags: row-major fp16 IS the 16x16x32 A layout (row=l4, k=quad*8+j)
  half8 aq[4];
  {
    const _Float16* qr =
        qfo + ((size_t)h * NROWS + q0 + wave * 16 + l4) * DDIM + quad * 8;
#pragma unroll
    for (int t = 0; t < 4; t++) aq[t] = *(const half8*)(qr + t * 32);
  }

  float m_run[4];
#pragma unroll
  for (int r = 0; r < 4; r++) m_run[r] = -1e30f;
  floatx4 Oacc[8], lacc = (floatx4)0.f;
#pragma unroll
  for (int c = 0; c < 8; c++) Oacc[c] = (floatx4)0.f;

  half8 vones;
#pragma unroll
  for (int j = 0; j < 8; j++) vones[j] = (_Float16)1.f;

  const _Float16* kfo_h = kfo + (size_t)h * 64 * 8192;
  const _Float16* vfo_h = vfo + (size_t)h * 64 * 8192;
  const int lq = (l4 * 4 + (quad ^ ((l4 >> 1) & 3))) * 8;
  const int kt0 = s * 32, kt1 = kt0 + 32;

  char* const pbase = (char*)&lds.p[wave][0];

  // preload K(kt0) into buffer 0 (kt0 is even for both s)
  {
    const _Float16* ks = kfo_h + (size_t)kt0 * 8192 + wave * 2048 + lane * 8;
    _Float16* kd = &lds.k[0][wave * 2048];
#pragma unroll
    for (int it = 0; it < 4; it++) async_cp16(ks + it * 512, kd + it * 512);
  }

  for (int kt = kt0; kt < kt1; ++kt) {
    const int cur = kt & 1;
    __syncthreads();  // drains K(kt) copies; all waves done with k[cur^1]

    // ---- prefetch K(kt+1) into the other buffer ----
    if (kt + 1 < kt1) {
      const _Float16* ks = kfo_h + (size_t)(kt + 1) * 8192 + wave * 2048 + lane * 8;
      _Float16* kd = &lds.k[cur ^ 1][wave * 2048];
#pragma unroll
      for (int it = 0; it < 4; it++) async_cp16(ks + it * 512, kd + it * 512);
    }

    // ---- S = Q @ K^T (K from LDS buffer cur); S is in base-2 units ----
    floatx4 Sf[4];
#pragma unroll
    for (int c = 0; c < 4; c++) Sf[c] = (floatx4)0.f;
    __builtin_amdgcn_s_setprio(1);
#pragma unroll
    for (int t = 0; t < 4; t++) {
      half8 b[4];
#pragma unroll
      for (int c = 0; c < 4; c++)
        b[c] = *(const half8*)&lds.k[cur][(c * 4 + t) * 512 + lq];
#pragma unroll
      for (int c = 0; c < 4; c++)
        Sf[c] = __builtin_amdgcn_mfma_f32_16x16x32_f16(aq[t], b[c], Sf[c], 0, 0, 0);
    }
    __builtin_amdgcn_s_setprio(0);

    // ---- register softmax (base-2): row r lives in 16 lanes (fixed quad) ----
    float alpha[4];
    {
      float mt[4];
#pragma unroll
      for (int r = 0; r < 4; r++)
        mt[r] = fmaxf(fmaxf(Sf[0][r], Sf[1][r]), fmaxf(Sf[2][r], Sf[3][r]));
#pragma unroll
      for (int mk = 1; mk <= 8; mk <<= 1)
#pragma unroll
        for (int r = 0; r < 4; r++) mt[r] = fmaxf(mt[r], __shfl_xor(mt[r], mk, 64));
#pragma unroll
      for (int r = 0; r < 4; r++) {
        const float mn = fmaxf(m_run[r], mt[r]);
        alpha[r] = __ocml_native_exp2_f32(m_run[r] - mn);
        m_run[r] = mn;
      }
#pragma unroll
      for (int r = 0; r < 4; r++)
#pragma unroll
        for (int c = 0; c < 4; c++)
          Sf[c][r] = __ocml_native_exp2_f32(Sf[c][r] - m_run[r]);
    }

    // ---- P: C-layout -> A-layout, wave-private LDS, XOR-swizzled rows ----
#pragma unroll
    for (int c = 0; c < 4; c++)
#pragma unroll
      for (int r = 0; r < 4; r++) {
        const int row_s = (c * 2 + (l4 >> 3)) * 16 + quad * 4 + r;
        const int byte_s = (row_s * 16 + (l4 & 7) * 2) ^ (((row_s >> 3) & 3) << 5);
        *(_Float16*)(pbase + byte_s) = (_Float16)Sf[c][r];
      }

    // ---- V frags: global (L1/L2) -> registers.  Issued here (after Sf is
    // dead) so their live range spans only rescale+PV. ----
    half8 vfrag[8][2];
    {
      const _Float16* vtb = vfo_h + (size_t)kt * 8192;
#pragma unroll
      for (int c = 0; c < 8; c++)
#pragma unroll
        for (int t = 0; t < 2; t++)
          vfrag[c][t] = *(const half8*)(vtb + (c * 2 + t) * 512 + lq);
    }

    // ---- rescale O/l only when the running max moved ----
    {
      const bool moved = (alpha[0] != 1.f) | (alpha[1] != 1.f) |
                         (alpha[2] != 1.f) | (alpha[3] != 1.f);
      if (__any(moved)) {
#pragma unroll
        for (int c = 0; c < 8; c++) {
          Oacc[c][0] *= alpha[0]; Oacc[c][1] *= alpha[1];
          Oacc[c][2] *= alpha[2]; Oacc[c][3] *= alpha[3];
        }
        lacc[0] *= alpha[0]; lacc[1] *= alpha[1];
        lacc[2] *= alpha[2]; lacc[3] *= alpha[3];
      }
    }

    // ---- O += P@V (V from registers), l += P@ones ----
    __builtin_amdgcn_s_setprio(1);
#pragma unroll
    for (int t = 0; t < 2; t++) {
      const int row_r = (t * 4 + quad) * 16 + l4;
      const int byte_r = (row_r * 16) ^ (((row_r >> 3) & 3) << 5);
      half8 ap = *(const half8*)(pbase + byte_r);
      lacc = __builtin_amdgcn_mfma_f32_16x16x32_f16(ap, vones, lacc, 0, 0, 0);
#pragma unroll
      for (int c = 0; c < 8; c++)
        Oacc[c] = __builtin_amdgcn_mfma_f32_16x16x32_f16(ap, vfrag[c][t], Oacc[c], 0, 0, 0);
    }
    __builtin_amdgcn_s_setprio(0);
    // no trailing barrier: next iteration's barrier covers both hazards
  }

  // ---- epilogue: unnormalized partial O (fp16) + per-row (m, l) ----
  const int rbase = wave * 16 + quad * 4;
  const size_t rowbase = (size_t)(s * NHEAD + h) * NROWS + q0 + rbase;
#pragma unroll
  for (int c = 0; c < 8; c++) {
    const int col = c * 16 + l4;
#pragma unroll
    for (int r = 0; r < 4; r++)
      op[(rowbase + r) * DDIM + col] = (_Float16)Oacc[c][r];
  }
  if (l4 == 0) {
#pragma unroll
    for (int r = 0; r < 4; r++) {
      mb[rowbase + r] = m_run[r];
      lb[rowbase + r] = lacc[r];
    }
  }
}

// ---------------------------------------------------------------------------
// Kernel 3: merge 2 split-K partials + head-sum -> u. grid 4096, block 128.
// m values are in base-2 units -> exp2 here.
// ---------------------------------------------------------------------------
__global__ __launch_bounds__(128) void merge_kernel(
    const _Float16* __restrict__ op, const float* __restrict__ mb,
    const float* __restrict__ lb, const float* __restrict__ Wm,
    float* __restrict__ u)
{
  __shared__ float sc[2][NHEAD];
  const int n = blockIdx.x, d = threadIdx.x;
  if (d < NHEAD) {
    const int h = d;
    const float m1 = mb[(size_t)h * NROWS + n];
    const float m2 = mb[(size_t)(NHEAD + h) * NROWS + n];
    const float l1 = lb[(size_t)h * NROWS + n];
    const float l2 = lb[(size_t)(NHEAD + h) * NROWS + n];
    const float m  = fmaxf(m1, m2);
    const float a1 = __ocml_native_exp2_f32(m1 - m);
    const float a2 = __ocml_native_exp2_f32(m2 - m);
    const float invL = Wm[h] / (l1 * a1 + l2 * a2);
    sc[0][h] = a1 * invL;
    sc[1][h] = a2 * invL;
  }
  __syncthreads();
  float acc = 0.f;
#pragma unroll
  for (int h = 0; h < NHEAD; h++) {
    acc += sc[0][h] * (float)op[((size_t)h * NROWS + n) * DDIM + d];
    acc += sc[1][h] * (float)op[((size_t)(NHEAD + h) * NROWS + n) * DDIM + d];
  }
  u[(size_t)n * DDIM + d] = acc;
}

// ---------------------------------------------------------------------------
// Kernel 4: y = x + relu((x+u) @ Wg^T + bg), 3-term bf16 MFMA, Wg in LDS.
// grid 64 (64-row tiles), block 256.
// ---------------------------------------------------------------------------
__global__ __launch_bounds__(256, 2) void mlp_kernel(
    const float* __restrict__ x, const float* __restrict__ u,
    const float* __restrict__ Wg, const float* __restrict__ bg,
    float* __restrict__ out)
{
  __shared__ alignas(16) unsigned short wghi[DDIM][72];
  __shared__ alignas(16) unsigned short wglo[DDIM][72];
  const int tid = threadIdx.x, lane = tid & 63, wave = tid >> 6;
  const int l4 = lane & 15, quad = lane >> 4;
  const int r0 = blockIdx.x * 64;

  floatx4 acc[8];
#pragma unroll
  for (int c = 0; c < 8; c++) acc[c] = (floatx4)0.f;

  for (int fh = 0; fh < 2; fh++) {
    for (int i = tid; i < DDIM * 64; i += 256) {
      const int ii = i >> 6, jl = i & 63;
      unsigned short hi, lo;
      split2(Wg[ii * DDIM + fh * 64 + jl], hi, lo);
      wghi[ii][jl] = hi; wglo[ii][jl] = lo;
    }
    __syncthreads();

    const size_t xoff = (size_t)(r0 + wave * 16 + l4) * DDIM + fh * 64 + quad * 8;
    short8 ah[2], al[2];
#pragma unroll
    for (int t2 = 0; t2 < 2; t2++) {
      float4 x0 = *(const float4*)(x + xoff + t2 * 32);
      float4 x1 = *(const float4*)(x + xoff + t2 * 32 + 4);
      float4 u0 = *(const float4*)(u + xoff + t2 * 32);
      float4 u1 = *(const float4*)(u + xoff + t2 * 32 + 4);
      float hv[8] = {x0.x + u0.x, x0.y + u0.y, x0.z + u0.z, x0.w + u0.w,
                     x1.x + u1.x, x1.y + u1.y, x1.z + u1.z, x1.w + u1.w};
#pragma unroll
      for (int j = 0; j < 8; j++) {
        unsigned short hi, lo; split2(hv[j], hi, lo);
        ah[t2][j] = (short)hi; al[t2][j] = (short)lo;
      }
    }
#pragma unroll
    for (int t2 = 0; t2 < 2; t2++) {
#pragma unroll
      for (int c = 0; c < 8; c++) {
        short8 bh = *(const short8*)(&wghi[c * 16 + l4][t2 * 32 + quad * 8]);
        short8 bl = *(const short8*)(&wglo[c * 16 + l4][t2 * 32 + quad * 8]);
        acc[c] = __builtin_amdgcn_mfma_f32_16x16x32_bf16(ah[t2], bh, acc[c], 0, 0, 0);
        acc[c] = __builtin_amdgcn_mfma_f32_16x16x32_bf16(al[t2], bh, acc[c], 0, 0, 0);
        acc[c] = __builtin_amdgcn_mfma_f32_16x16x32_bf16(ah[t2], bl, acc[c], 0, 0, 0);
      }
    }
    __syncthreads();
  }

  const int rbase = wave * 16 + quad * 4;
#pragma unroll
  for (int c = 0; c < 8; c++) {
    const int col = c * 16 + l4;
    const float bgf = bg[col];
#pragma unroll
    for (int r = 0; r < 4; r++) {
      const size_t idx = (size_t)(r0 + rbase + r) * DDIM + col;
      out[idx] = x[idx] + fmaxf(acc[c][r] + bgf, 0.f);
    }
  }
}

extern "C" void kernel_launch(void* const* d_in, const int* in_sizes, int n_in,
                              void* d_out, int out_size, void* d_ws, size_t ws_size,
                              hipStream_t stream) {
  float* out = (float*)d_out;
  const int fill_blocks = (out_size + 255) / 256;

  const bool ok_sizes =
      n_in == 7 &&
      in_sizes[0] == NROWS * DDIM &&
      in_sizes[1] == NHEAD * DDIM * DDIM &&
      in_sizes[2] == NHEAD * DDIM * DDIM &&
      in_sizes[3] == NHEAD * DDIM * DDIM &&
      in_sizes[4] == NHEAD &&
      in_sizes[5] == DDIM * DDIM &&
      in_sizes[6] == DDIM &&
      out_size == NROWS * DDIM;
  if (!ok_sizes) {
    fill_kernel<<<fill_blocks, 256, 0, stream>>>(out, 1000.f, out_size);
    return;
  }

  // ws: u 2MB + kfo 8.4 + vfo 8.4 + qfo 8.4 + op(2) 16.8 + mb/lb 0.5 = 44.6MB
  const size_t HND = (size_t)NHEAD * NROWS * DDIM;
  const size_t ND  = (size_t)NROWS * DDIM;
  const size_t need = ND * 4 + 3 * HND * 2 + 2 * HND * 2 + 2 * NHEAD * NROWS * 8;
  if (ws_size < need) {
    fill_kernel<<<fill_blocks, 256, 0, stream>>>(out, 500.f, out_size);
    return;
  }

  const float* x  = (const float*)d_in[0];
  const float* Wk = (const float*)d_in[1];
  const float* Wq = (const float*)d_in[2];
  const float* Wv = (const float*)d_in[3];
  const float* Wm = (const float*)d_in[4];
  const float* Wg = (const float*)d_in[5];
  const float* bg = (const float*)d_in[6];

  float*     u   = (float*)d_ws;
  _Float16*  kfo = (_Float16*)(u + ND);
  _Float16*  vfo = kfo + HND;
  _Float16*  qfo = vfo + HND;
  _Float16*  op  = qfo + HND;
  float*     mb  = (float*)(op + 2 * HND);
  float*     lb  = mb + 2 * NHEAD * NROWS;

  (void)hipGetLastError();
  proj_kernel<<<dim3(16, NHEAD, 3), 256, 0, stream>>>(x, Wk, Wv, Wq, kfo, vfo, qfo);
  flash_kernel<<<dim3(1024), 256, 0, stream>>>(qfo, kfo, vfo, op, mb, lb);
  merge_kernel<<<dim3(4096), 128, 0, stream>>>(op, mb, lb, Wm, u);
  mlp_kernel<<<dim3(64), 256, 0, stream>>>(x, u, Wg, bg, out);
  if (hipGetLastError() != hipSuccess) {
    fill_kernel<<<fill_blocks, 256, 0, stream>>>(out, 2000.f, out_size);
  }
}

// Round 4
// 233.871 us; speedup vs baseline: 1.6626x; 1.6626x over previous
//
#include <hip/hip_runtime.h>

#define NROWS 4096
#define DDIM  128
#define NHEAD 8
#define LOG2E 1.44269504088896f

// native 2^x  ->  single v_exp_f32 (ocml symbol always present in device libs)
extern "C" __device__ float __ocml_native_exp2_f32(float);

typedef __attribute__((ext_vector_type(8))) short    short8;
typedef __attribute__((ext_vector_type(8))) _Float16 half8;
typedef __attribute__((ext_vector_type(4))) float    floatx4;

__device__ __forceinline__ float bf2f(unsigned short u){
  unsigned v = ((unsigned)u) << 16;
  return __builtin_bit_cast(float, v);
}
__device__ __forceinline__ unsigned short f2bf(float f){
  unsigned u = __builtin_bit_cast(unsigned, f);
  u += 0x7FFFu + ((u >> 16) & 1u);
  return (unsigned short)(u >> 16);
}
__device__ __forceinline__ void split2(float v, unsigned short& hi, unsigned short& lo){
  hi = f2bf(v);
  lo = f2bf(v - bf2f(hi));
}
// async global->LDS, 16B per lane: LDS dest = wave-uniform base + lane*16.
__device__ __forceinline__ void async_cp16(const void* g, void* l){
  __builtin_amdgcn_global_load_lds(
      (const __attribute__((address_space(1))) void*)g,
      (__attribute__((address_space(3))) void*)l, 16, 0, 0);
}

// fp32 sentinels: 500=ws too small, 1000=in_sizes mismatch, 2000=launch fail.
__global__ void fill_kernel(float* __restrict__ out, float val, int n){
  int i = blockIdx.x * 256 + threadIdx.x;
  if (i < n) out[i] = val;
}

// ---------------------------------------------------------------------------
// Kernel 0: prep — one-time bf16 hi/lo splits so proj/mlp do ZERO split2 VALU.
// W tiles stored in LDS-LINEAR chunk order with XOR swizzle baked in:
//   chunk L = d*8+m  holds  T[d][(m^(d&7))*8 + j],  j=0..7
//   proj T[d][k] = W[(fh*64+k)*128 + d] (W^T tile);  mlp T[d][k]=Wg[d*128+fh*64+k]
// Readers use idx = (col*8 + (k8 ^ (col&7)))*8 — same content as the old
// padded-LDS layout, but stageable by global_load_lds (lane-linear dest).
// x split to xh/xl row-major bf16 (direct short8 A-frag loads).
// ---------------------------------------------------------------------------
__global__ __launch_bounds__(256) void prep_kernel(
    const float* __restrict__ Wk, const float* __restrict__ Wv,
    const float* __restrict__ Wq, const float* __restrict__ Wg,
    const float* __restrict__ x,
    unsigned short* __restrict__ wpre, unsigned short* __restrict__ wgpre,
    unsigned short* __restrict__ xh, unsigned short* __restrict__ xl)
{
  const int id = blockIdx.x * 256 + threadIdx.x;
  if (id < 49152) {              // W_k/v/q: 3 z * 8 h * 2 fh * 1024 chunks
    const int z = id >> 14, rem = id & 16383;
    const int h = rem >> 11, rem2 = rem & 2047;
    const int fh = rem2 >> 10, L = rem2 & 1023;
    const int d = L >> 3, m = L & 7;
    const int kk0 = (m ^ (d & 7)) << 3;
    const float* W = (z == 0 ? Wk : (z == 1 ? Wv : Wq)) + h * DDIM * DDIM;
    short8 hi8, lo8;
#pragma unroll
    for (int j = 0; j < 8; j++) {
      unsigned short hi, lo;
      split2(W[(fh * 64 + kk0 + j) * DDIM + d], hi, lo);
      hi8[j] = (short)hi; lo8[j] = (short)lo;
    }
    unsigned short* base = wpre + (size_t)((z * 8 + h) * 2 + fh) * 16384;
    *(short8*)(base + L * 8) = hi8;
    *(short8*)(base + 8192 + L * 8) = lo8;
  } else if (id < 51200) {       // Wg: 2 fh * 1024 chunks
    const int t = id - 49152;
    const int fh = t >> 10, L = t & 1023;
    const int d = L >> 3, m = L & 7;
    const int kk0 = (m ^ (d & 7)) << 3;
    short8 hi8, lo8;
#pragma unroll
    for (int j = 0; j < 8; j++) {
      unsigned short hi, lo;
      split2(Wg[d * DDIM + fh * 64 + kk0 + j], hi, lo);
      hi8[j] = (short)hi; lo8[j] = (short)lo;
    }
    unsigned short* base = wgpre + fh * 16384;
    *(short8*)(base + L * 8) = hi8;
    *(short8*)(base + 8192 + L * 8) = lo8;
  } else if (id < 116736) {      // x: 65536 chunks of 8
    const int t = id - 51200;
    const float* src = x + (size_t)t * 8;
    float4 v0 = *(const float4*)src, v1 = *(const float4*)(src + 4);
    float xv[8] = {v0.x, v0.y, v0.z, v0.w, v1.x, v1.y, v1.z, v1.w};
    short8 hi8, lo8;
#pragma unroll
    for (int j = 0; j < 8; j++) {
      unsigned short hi, lo; split2(xv[j], hi, lo);
      hi8[j] = (short)hi; lo8[j] = (short)lo;
    }
    *(short8*)(xh + (size_t)t * 8) = hi8;
    *(short8*)(xl + (size_t)t * 8) = lo8;
  }
}

// ---------------------------------------------------------------------------
// Kernel 1: k = x@Wk[h], v = x@Wv[h], q = x@Wq[h]*log2e — from pre-split
// inputs.  W staged via global_load_lds (no VALU), x frags loaded as short8.
// k/v: fp16 outputs in MFMA fragment order with bank swizzle baked in.
// q: row-major fp16 (== 16x16x32 A-frag order), pre-scaled by log2(e).
// 3-term bf16 MFMA. grid (16, NHEAD, 3): four 64-row tiles per block.
// ---------------------------------------------------------------------------
__global__ __launch_bounds__(256, 2) void proj_kernel(
    const unsigned short* __restrict__ xh, const unsigned short* __restrict__ xl,
    const unsigned short* __restrict__ wpre,
    _Float16* __restrict__ kfo, _Float16* __restrict__ vfo,
    _Float16* __restrict__ qfo)
{
  __shared__ alignas(16) unsigned short whi[8192];
  __shared__ alignas(16) unsigned short wlo[8192];
  const int tid = threadIdx.x, lane = tid & 63, wave = tid >> 6;
  const int l4 = lane & 15, quad = lane >> 4;
  const int h = blockIdx.y, z = blockIdx.z;
  const unsigned short* wb = wpre + (size_t)((z * 8 + h) * 2) * 16384;

  floatx4 acc[4][8];
#pragma unroll
  for (int t4 = 0; t4 < 4; t4++)
#pragma unroll
    for (int c = 0; c < 8; c++) acc[t4][c] = (floatx4)0.f;

  for (int fh = 0; fh < 2; fh++) {
    {
      const unsigned short* src = wb + fh * 16384;
      const unsigned short* sh = src + wave * 2048 + lane * 8;
      const unsigned short* sl = src + 8192 + wave * 2048 + lane * 8;
      unsigned short* dh = &whi[wave * 2048];
      unsigned short* dl = &wlo[wave * 2048];
#pragma unroll
      for (int it = 0; it < 4; it++) {
        async_cp16(sh + it * 512, dh + it * 512);
        async_cp16(sl + it * 512, dl + it * 512);
      }
    }
    __syncthreads();  // compiler drains vmcnt before barrier

#pragma unroll
    for (int t4 = 0; t4 < 4; t4++) {
      const int row = blockIdx.x * 256 + t4 * 64 + wave * 16 + l4;
      const size_t xo = (size_t)row * DDIM + fh * 64 + quad * 8;
      short8 ah[2], al[2];
      ah[0] = *(const short8*)(xh + xo);
      ah[1] = *(const short8*)(xh + xo + 32);
      al[0] = *(const short8*)(xl + xo);
      al[1] = *(const short8*)(xl + xo + 32);
#pragma unroll
      for (int t2 = 0; t2 < 2; t2++) {
#pragma unroll
        for (int c = 0; c < 8; c++) {
          const int col = c * 16 + l4;
          const int idx = (col * 8 + ((t2 * 4 + quad) ^ (col & 7))) * 8;
          short8 bh = *(const short8*)&whi[idx];
          short8 bl = *(const short8*)&wlo[idx];
          acc[t4][c] = __builtin_amdgcn_mfma_f32_16x16x32_bf16(ah[t2], bh, acc[t4][c], 0, 0, 0);
          acc[t4][c] = __builtin_amdgcn_mfma_f32_16x16x32_bf16(al[t2], bh, acc[t4][c], 0, 0, 0);
          acc[t4][c] = __builtin_amdgcn_mfma_f32_16x16x32_bf16(ah[t2], bl, acc[t4][c], 0, 0, 0);
        }
      }
    }
    __syncthreads();
  }

  const int rb = wave * 16 + quad * 4;
#pragma unroll
  for (int t4 = 0; t4 < 4; t4++) {
    const int tile = blockIdx.x * 4 + t4;
    const size_t tilebase = (size_t)(h * 64 + tile) * 8192;
#pragma unroll
    for (int c = 0; c < 8; c++) {
      const int d = c * 16 + l4;
#pragma unroll
      for (int r = 0; r < 4; r++) {
        const int kl = rb + r;
        const float val = acc[t4][c][r];
        if (z == 0) {
          const int c2 = kl >> 4, l4k = kl & 15;
          const int tt = d >> 5, qd = (d >> 3) & 3, jj = d & 7;
          const int qX = qd ^ ((l4k >> 1) & 3);
          kfo[tilebase + (size_t)((c2 * 4 + tt) * 16 + l4k) * 32 + qX * 8 + jj] =
              (_Float16)val;
        } else if (z == 1) {
          const int c2 = d >> 4, l4v = d & 15;
          const int tt = kl >> 5, qd = (kl >> 3) & 3, jj = kl & 7;
          const int qX = qd ^ ((l4v >> 1) & 3);
          vfo[tilebase + (size_t)((c2 * 2 + tt) * 16 + l4v) * 32 + qX * 8 + jj] =
              (_Float16)val;
        } else {
          // q: row-major fp16, scaled by log2(e) for base-2 softmax
          qfo[((size_t)h * NROWS + (size_t)tile * 64 + kl) * DDIM + d] =
              (_Float16)(val * LOG2E);
        }
      }
    }
  }
}

// ---------------------------------------------------------------------------
// Kernel 2: flash attention. 64 q-rows/block, SPLIT-K x3.
// grid 1536: h=bid&7 (XCD-affine), qt=(bid>>3)&63, s=bid>>9 (kt ranges
// [0,22)/[22,43)/[43,64)).  3 blocks/CU (VGPR-bound) * 256 CU = 768 slots;
// 1536 = 2*768 exactly -> two full residency waves, NO drain tail (round-2's
// 1024 grid ran its last quarter at 1/3 occupancy).
// __launch_bounds__(256,3): round-2 proven no-spill (VGPR=80).  (256,4)
// spills — unified VGPR+AGPR file: 36 AGPR acc + ~80 arch > 128 cap
// (measured twice: rounds 1 & 3).
// K double-buffered in LDS via global_load_lds, ONE barrier/iter; V frags
// global->reg after P-store (short live range).  Base-2 softmax.
// s_setprio(1) around MFMA clusters (independent blocks -> m191 regime).
// ---------------------------------------------------------------------------
struct FlashLds {
  _Float16 k[2][8192];  // 32768 B
  _Float16 p[4][1024];  // 8192 B, wave-private P tile [kblk8][qrow16][8]
};

__global__ __launch_bounds__(256, 3) void flash_kernel(
    const _Float16* __restrict__ qfo, const _Float16* __restrict__ kfo,
    const _Float16* __restrict__ vfo,
    _Float16* __restrict__ op, float* __restrict__ mb, float* __restrict__ lb)
{
  __shared__ alignas(16) FlashLds lds;
  const int tid = threadIdx.x, lane = tid & 63, wave = tid >> 6;
  const int l4 = lane & 15, quad = lane >> 4;
  const int h = blockIdx.x & 7, qt = (blockIdx.x >> 3) & 63, s = blockIdx.x >> 9;
  const int q0 = qt * 64;

  // Q A-frags: row-major fp16 IS the 16x16x32 A layout (row=l4, k=quad*8+j)
  half8 aq[4];
  {
    const _Float16* qr =
        qfo + ((size_t)h * NROWS + q0 + wave * 16 + l4) * DDIM + quad * 8;
#pragma unroll
    for (int t = 0; t < 4; t++) aq[t] = *(const half8*)(qr + t * 32);
  }

  float m_run[4];
#pragma unroll
  for (int r = 0; r < 4; r++) m_run[r] = -1e30f;
  floatx4 Oacc[8], lacc = (floatx4)0.f;
#pragma unroll
  for (int c = 0; c < 8; c++) Oacc[c] = (floatx4)0.f;

  half8 vones;
#pragma unroll
  for (int j = 0; j < 8; j++) vones[j] = (_Float16)1.f;

  const _Float16* kfo_h = kfo + (size_t)h * 64 * 8192;
  const _Float16* vfo_h = vfo + (size_t)h * 64 * 8192;
  const int lq = (l4 * 4 + (quad ^ ((l4 >> 1) & 3))) * 8;
  const int kt0 = (s == 0) ? 0 : (s == 1 ? 22 : 43);
  const int kt1 = (s == 0) ? 22 : (s == 1 ? 43 : 64);

  // preload K(kt0) into buffer kt0&1 (parity-consistent with the loop)
  {
    const _Float16* ks = kfo_h + (size_t)kt0 * 8192 + wave * 2048 + lane * 8;
    _Float16* kd = &lds.k[kt0 & 1][wave * 2048];
#pragma unroll
    for (int it = 0; it < 4; it++) async_cp16(ks + it * 512, kd + it * 512);
  }

  for (int kt = kt0; kt < kt1; ++kt) {
    const int cur = kt & 1;
    __syncthreads();  // drains K(kt) copies; all waves done with k[cur^1]

    // ---- prefetch K(kt+1) into the other buffer ----
    if (kt + 1 < kt1) {
      const _Float16* ks = kfo_h + (size_t)(kt + 1) * 8192 + wave * 2048 + lane * 8;
      _Float16* kd = &lds.k[cur ^ 1][wave * 2048];
#pragma unroll
      for (int it = 0; it < 4; it++) async_cp16(ks + it * 512, kd + it * 512);
    }

    // ---- S = Q @ K^T (K from LDS buffer cur); S is in base-2 units ----
    floatx4 Sf[4];
#pragma unroll
    for (int c = 0; c < 4; c++) Sf[c] = (floatx4)0.f;
    __builtin_amdgcn_s_setprio(1);
#pragma unroll
    for (int t = 0; t < 4; t++) {
      half8 b[4];
#pragma unroll
      for (int c = 0; c < 4; c++)
        b[c] = *(const half8*)&lds.k[cur][(c * 4 + t) * 512 + lq];
#pragma unroll
      for (int c = 0; c < 4; c++)
        Sf[c] = __builtin_amdgcn_mfma_f32_16x16x32_f16(aq[t], b[c], Sf[c], 0, 0, 0);
    }
    __builtin_amdgcn_s_setprio(0);

    // ---- register softmax (base-2): row r lives in 16 lanes (fixed quad) ----
    float alpha[4];
    {
      float mt[4];
#pragma unroll
      for (int r = 0; r < 4; r++)
        mt[r] = fmaxf(fmaxf(Sf[0][r], Sf[1][r]), fmaxf(Sf[2][r], Sf[3][r]));
#pragma unroll
      for (int mk = 1; mk <= 8; mk <<= 1)
#pragma unroll
        for (int r = 0; r < 4; r++) mt[r] = fmaxf(mt[r], __shfl_xor(mt[r], mk, 64));
#pragma unroll
      for (int r = 0; r < 4; r++) {
        const float mn = fmaxf(m_run[r], mt[r]);
        alpha[r] = __ocml_native_exp2_f32(m_run[r] - mn);
        m_run[r] = mn;
      }
#pragma unroll
      for (int r = 0; r < 4; r++)
#pragma unroll
        for (int c = 0; c < 4; c++)
          Sf[c][r] = __ocml_native_exp2_f32(Sf[c][r] - m_run[r]);
    }

    // ---- P: C-layout -> A-layout via wave-private frag-ordered LDS ----
#pragma unroll
    for (int c = 0; c < 4; c++)
#pragma unroll
      for (int r = 0; r < 4; r++)
        lds.p[wave][((c * 2 + (l4 >> 3)) * 16 + quad * 4 + r) * 8 + (l4 & 7)] =
            (_Float16)Sf[c][r];

    // ---- V frags: global (L1/L2) -> registers (short live range) ----
    half8 vfrag[8][2];
    {
      const _Float16* vtb = vfo_h + (size_t)kt * 8192;
#pragma unroll
      for (int c = 0; c < 8; c++)
#pragma unroll
        for (int t = 0; t < 2; t++)
          vfrag[c][t] = *(const half8*)(vtb + (c * 2 + t) * 512 + lq);
    }

    // ---- rescale O/l only when the running max moved ----
    {
      const bool moved = (alpha[0] != 1.f) | (alpha[1] != 1.f) |
                         (alpha[2] != 1.f) | (alpha[3] != 1.f);
      if (__any(moved)) {
#pragma unroll
        for (int c = 0; c < 8; c++) {
          Oacc[c][0] *= alpha[0]; Oacc[c][1] *= alpha[1];
          Oacc[c][2] *= alpha[2]; Oacc[c][3] *= alpha[3];
        }
        lacc[0] *= alpha[0]; lacc[1] *= alpha[1];
        lacc[2] *= alpha[2]; lacc[3] *= alpha[3];
      }
    }

    // ---- O += P@V (V from registers), l += P@ones ----
    __builtin_amdgcn_s_setprio(1);
#pragma unroll
    for (int t = 0; t < 2; t++) {
      half8 ap = *(const half8*)&lds.p[wave][((t * 4 + quad) * 16 + l4) * 8];
      lacc = __builtin_amdgcn_mfma_f32_16x16x32_f16(ap, vones, lacc, 0, 0, 0);
#pragma unroll
      for (int c = 0; c < 8; c++)
        Oacc[c] = __builtin_amdgcn_mfma_f32_16x16x32_f16(ap, vfrag[c][t], Oacc[c], 0, 0, 0);
    }
    __builtin_amdgcn_s_setprio(0);
    // no trailing barrier: next iteration's barrier covers both hazards
  }

  // ---- epilogue: unnormalized partial O (fp16) + per-row (m, l) ----
  const int rbase = wave * 16 + quad * 4;
  const size_t rowbase = (size_t)(s * NHEAD + h) * NROWS + q0 + rbase;
#pragma unroll
  for (int c = 0; c < 8; c++) {
    const int col = c * 16 + l4;
#pragma unroll
    for (int r = 0; r < 4; r++)
      op[(rowbase + r) * DDIM + col] = (_Float16)Oacc[c][r];
  }
  if (l4 == 0) {
#pragma unroll
    for (int r = 0; r < 4; r++) {
      mb[rowbase + r] = m_run[r];
      lb[rowbase + r] = lacc[r];
    }
  }
}

// ---------------------------------------------------------------------------
// Kernel 3: merge 3 split-K partials + head-sum -> u. grid 4096, block 128.
// m values are in base-2 units -> exp2 here.
// ---------------------------------------------------------------------------
__global__ __launch_bounds__(128) void merge_kernel(
    const _Float16* __restrict__ op, const float* __restrict__ mb,
    const float* __restrict__ lb, const float* __restrict__ Wm,
    float* __restrict__ u)
{
  __shared__ float sc[3][NHEAD];
  const int n = blockIdx.x, d = threadIdx.x;
  if (d < NHEAD) {
    const int h = d;
    float m0 = mb[(size_t)(0 * NHEAD + h) * NROWS + n];
    float m1 = mb[(size_t)(1 * NHEAD + h) * NROWS + n];
    float m2 = mb[(size_t)(2 * NHEAD + h) * NROWS + n];
    float l0 = lb[(size_t)(0 * NHEAD + h) * NROWS + n];
    float l1 = lb[(size_t)(1 * NHEAD + h) * NROWS + n];
    float l2 = lb[(size_t)(2 * NHEAD + h) * NROWS + n];
    const float m = fmaxf(fmaxf(m0, m1), m2);
    const float a0 = __ocml_native_exp2_f32(m0 - m);
    const float a1 = __ocml_native_exp2_f32(m1 - m);
    const float a2 = __ocml_native_exp2_f32(m2 - m);
    const float invL = Wm[h] / (l0 * a0 + l1 * a1 + l2 * a2);
    sc[0][h] = a0 * invL;
    sc[1][h] = a1 * invL;
    sc[2][h] = a2 * invL;
  }
  __syncthreads();
  float acc = 0.f;
#pragma unroll
  for (int s = 0; s < 3; s++)
#pragma unroll
    for (int h = 0; h < NHEAD; h++)
      acc += sc[s][h] * (float)op[((size_t)(s * NHEAD + h) * NROWS + n) * DDIM + d];
  u[(size_t)n * DDIM + d] = acc;
}

// ---------------------------------------------------------------------------
// Kernel 4: y = x + relu((x+u) @ Wg^T + bg), 3-term bf16 MFMA.
// Wg pre-split: staged via global_load_lds (no VALU).  grid 64, block 256.
// ---------------------------------------------------------------------------
__global__ __launch_bounds__(256, 2) void mlp_kernel(
    const float* __restrict__ x, const float* __restrict__ u,
    const unsigned short* __restrict__ wgpre, const float* __restrict__ bg,
    float* __restrict__ out)
{
  __shared__ alignas(16) unsigned short whi[8192];
  __shared__ alignas(16) unsigned short wlo[8192];
  const int tid = threadIdx.x, lane = tid & 63, wave = tid >> 6;
  const int l4 = lane & 15, quad = lane >> 4;
  const int r0 = blockIdx.x * 64;

  floatx4 acc[8];
#pragma unroll
  for (int c = 0; c < 8; c++) acc[c] = (floatx4)0.f;

  for (int fh = 0; fh < 2; fh++) {
    {
      const unsigned short* src = wgpre + fh * 16384;
      const unsigned short* sh = src + wave * 2048 + lane * 8;
      const unsigned short* sl = src + 8192 + wave * 2048 + lane * 8;
      unsigned short* dh = &whi[wave * 2048];
      unsigned short* dl = &wlo[wave * 2048];
#pragma unroll
      for (int it = 0; it < 4; it++) {
        async_cp16(sh + it * 512, dh + it * 512);
        async_cp16(sl + it * 512, dl + it * 512);
      }
    }
    __syncthreads();

    const size_t xoff = (size_t)(r0 + wave * 16 + l4) * DDIM + fh * 64 + quad * 8;
    short8 ah[2], al[2];
#pragma unroll
    for (int t2 = 0; t2 < 2; t2++) {
      float4 x0 = *(const float4*)(x + xoff + t2 * 32);
      float4 x1 = *(const float4*)(x + xoff + t2 * 32 + 4);
      float4 u0 = *(const float4*)(u + xoff + t2 * 32);
      float4 u1 = *(const float4*)(u + xoff + t2 * 32 + 4);
      float hv[8] = {x0.x + u0.x, x0.y + u0.y, x0.z + u0.z, x0.w + u0.w,
                     x1.x + u1.x, x1.y + u1.y, x1.z + u1.z, x1.w + u1.w};
#pragma unroll
      for (int j = 0; j < 8; j++) {
        unsigned short hi, lo; split2(hv[j], hi, lo);
        ah[t2][j] = (short)hi; al[t2][j] = (short)lo;
      }
    }
#pragma unroll
    for (int t2 = 0; t2 < 2; t2++) {
#pragma unroll
      for (int c = 0; c < 8; c++) {
        const int col = c * 16 + l4;
        const int idx = (col * 8 + ((t2 * 4 + quad) ^ (col & 7))) * 8;
        short8 bh = *(const short8*)&whi[idx];
        short8 bl = *(const short8*)&wlo[idx];
        acc[c] = __builtin_amdgcn_mfma_f32_16x16x32_bf16(ah[t2], bh, acc[c], 0, 0, 0);
        acc[c] = __builtin_amdgcn_mfma_f32_16x16x32_bf16(al[t2], bh, acc[c], 0, 0, 0);
        acc[c] = __builtin_amdgcn_mfma_f32_16x16x32_bf16(ah[t2], bl, acc[c], 0, 0, 0);
      }
    }
    __syncthreads();
  }

  const int rbase = wave * 16 + quad * 4;
#pragma unroll
  for (int c = 0; c < 8; c++) {
    const int col = c * 16 + l4;
    const float bgf = bg[col];
#pragma unroll
    for (int r = 0; r < 4; r++) {
      const size_t idx = (size_t)(r0 + rbase + r) * DDIM + col;
      out[idx] = x[idx] + fmaxf(acc[c][r] + bgf, 0.f);
    }
  }
}

extern "C" void kernel_launch(void* const* d_in, const int* in_sizes, int n_in,
                              void* d_out, int out_size, void* d_ws, size_t ws_size,
                              hipStream_t stream) {
  float* out = (float*)d_out;
  const int fill_blocks = (out_size + 255) / 256;

  const bool ok_sizes =
      n_in == 7 &&
      in_sizes[0] == NROWS * DDIM &&
      in_sizes[1] == NHEAD * DDIM * DDIM &&
      in_sizes[2] == NHEAD * DDIM * DDIM &&
      in_sizes[3] == NHEAD * DDIM * DDIM &&
      in_sizes[4] == NHEAD &&
      in_sizes[5] == DDIM * DDIM &&
      in_sizes[6] == DDIM &&
      out_size == NROWS * DDIM;
  if (!ok_sizes) {
    fill_kernel<<<fill_blocks, 256, 0, stream>>>(out, 1000.f, out_size);
    return;
  }

  // ws: u 2MB + k/v/qfo 25.2 + op(3) 25.2 + mb/lb 0.8 + wpre 1.5 + wgpre 0.06
  //     + xh/xl 2.1  = ~57 MB
  const size_t HND = (size_t)NHEAD * NROWS * DDIM;
  const size_t ND  = (size_t)NROWS * DDIM;
  const size_t WPRE_N  = (size_t)3 * 8 * 2 * 16384;  // ushorts
  const size_t WGPRE_N = (size_t)2 * 16384;
  const size_t need = ND * 4 + 3 * HND * 2 + 3 * HND * 2 +
                      2 * (3 * (size_t)NHEAD * NROWS) * 4 +
                      (WPRE_N + WGPRE_N + 2 * ND) * 2;
  if (ws_size < need) {
    fill_kernel<<<fill_blocks, 256, 0, stream>>>(out, 500.f, out_size);
    return;
  }

  const float* x  = (const float*)d_in[0];
  const float* Wk = (const float*)d_in[1];
  const float* Wq = (const float*)d_in[2];
  const float* Wv = (const float*)d_in[3];
  const float* Wm = (const float*)d_in[4];
  const float* Wg = (const float*)d_in[5];
  const float* bg = (const float*)d_in[6];

  float*          u     = (float*)d_ws;
  _Float16*       kfo   = (_Float16*)(u + ND);
  _Float16*       vfo   = kfo + HND;
  _Float16*       qfo   = vfo + HND;
  _Float16*       op    = qfo + HND;                 // 3*HND
  float*          mb    = (float*)(op + 3 * HND);    // 3*NHEAD*NROWS
  float*          lb    = mb + 3 * NHEAD * NROWS;
  unsigned short* wpre  = (unsigned short*)(lb + 3 * NHEAD * NROWS);
  unsigned short* wgpre = wpre + WPRE_N;
  unsigned short* xh    = wgpre + WGPRE_N;
  unsigned short* xl    = xh + ND;

  (void)hipGetLastError();
  prep_kernel<<<dim3(456), 256, 0, stream>>>(Wk, Wv, Wq, Wg, x, wpre, wgpre, xh, xl);
  proj_kernel<<<dim3(16, NHEAD, 3), 256, 0, stream>>>(xh, xl, wpre, kfo, vfo, qfo);
  flash_kernel<<<dim3(1536), 256, 0, stream>>>(qfo, kfo, vfo, op, mb, lb);
  merge_kernel<<<dim3(4096), 128, 0, stream>>>(op, mb, lb, Wm, u);
  mlp_kernel<<<dim3(64), 256, 0, stream>>>(x, u, wgpre, bg, out);
  if (hipGetLastError() != hipSuccess) {
    fill_kernel<<<fill_blocks, 256, 0, stream>>>(out, 2000.f, out_size);
  }
}

// Round 5
// 231.722 us; speedup vs baseline: 1.6780x; 1.0093x over previous
//
#include <hip/hip_runtime.h>

#define NROWS 4096
#define DDIM  128
#define NHEAD 8
#define LOG2E 1.44269504088896f

// native 2^x  ->  single v_exp_f32 (ocml symbol always present in device libs)
extern "C" __device__ float __ocml_native_exp2_f32(float);

typedef __attribute__((ext_vector_type(8))) short    short8;
typedef __attribute__((ext_vector_type(8))) _Float16 half8;
typedef __attribute__((ext_vector_type(4))) float    floatx4;

__device__ __forceinline__ float bf2f(unsigned short u){
  unsigned v = ((unsigned)u) << 16;
  return __builtin_bit_cast(float, v);
}
__device__ __forceinline__ unsigned short f2bf(float f){
  unsigned u = __builtin_bit_cast(unsigned, f);
  u += 0x7FFFu + ((u >> 16) & 1u);
  return (unsigned short)(u >> 16);
}
__device__ __forceinline__ void split2(float v, unsigned short& hi, unsigned short& lo){
  hi = f2bf(v);
  lo = f2bf(v - bf2f(hi));
}
// async global->LDS, 16B per lane: LDS dest = wave-uniform base + lane*16.
__device__ __forceinline__ void async_cp16(const void* g, void* l){
  __builtin_amdgcn_global_load_lds(
      (const __attribute__((address_space(1))) void*)g,
      (__attribute__((address_space(3))) void*)l, 16, 0, 0);
}
// 16-lane (DPP row) max reduce via row_ror 8/4/2/1 — pure VALU, no lgkm.
__device__ __forceinline__ float dpp_max16(float v){
  int t;
  t = __builtin_amdgcn_update_dpp(0, __builtin_bit_cast(int, v), 0x128, 0xF, 0xF, false);
  v = fmaxf(v, __builtin_bit_cast(float, t));
  t = __builtin_amdgcn_update_dpp(0, __builtin_bit_cast(int, v), 0x124, 0xF, 0xF, false);
  v = fmaxf(v, __builtin_bit_cast(float, t));
  t = __builtin_amdgcn_update_dpp(0, __builtin_bit_cast(int, v), 0x122, 0xF, 0xF, false);
  v = fmaxf(v, __builtin_bit_cast(float, t));
  t = __builtin_amdgcn_update_dpp(0, __builtin_bit_cast(int, v), 0x121, 0xF, 0xF, false);
  v = fmaxf(v, __builtin_bit_cast(float, t));
  return v;
}

// fp32 sentinels: 500=ws too small, 1000=in_sizes mismatch, 2000=launch fail.
__global__ void fill_kernel(float* __restrict__ out, float val, int n){
  int i = blockIdx.x * 256 + threadIdx.x;
  if (i < n) out[i] = val;
}

// ---------------------------------------------------------------------------
// Kernel 0: prep — one-time bf16 hi/lo splits so proj/mlp do ZERO split2 VALU.
// W tiles stored in LDS-LINEAR chunk order with XOR swizzle baked in:
//   chunk L = d*8+m  holds  T[d][(m^(d&7))*8 + j],  j=0..7
//   proj T[d][k] = W[(fh*64+k)*128 + d] (W^T tile);  mlp T[d][k]=Wg[d*128+fh*64+k]
// Readers use idx = (col*8 + (k8 ^ (col&7)))*8.
// x split to xh/xl row-major bf16 (direct short8 A-frag loads).
// ---------------------------------------------------------------------------
__global__ __launch_bounds__(256) void prep_kernel(
    const float* __restrict__ Wk, const float* __restrict__ Wv,
    const float* __restrict__ Wq, const float* __restrict__ Wg,
    const float* __restrict__ x,
    unsigned short* __restrict__ wpre, unsigned short* __restrict__ wgpre,
    unsigned short* __restrict__ xh, unsigned short* __restrict__ xl)
{
  const int id = blockIdx.x * 256 + threadIdx.x;
  if (id < 49152) {              // W_k/v/q: 3 z * 8 h * 2 fh * 1024 chunks
    const int z = id >> 14, rem = id & 16383;
    const int h = rem >> 11, rem2 = rem & 2047;
    const int fh = rem2 >> 10, L = rem2 & 1023;
    const int d = L >> 3, m = L & 7;
    const int kk0 = (m ^ (d & 7)) << 3;
    const float* W = (z == 0 ? Wk : (z == 1 ? Wv : Wq)) + h * DDIM * DDIM;
    short8 hi8, lo8;
#pragma unroll
    for (int j = 0; j < 8; j++) {
      unsigned short hi, lo;
      split2(W[(fh * 64 + kk0 + j) * DDIM + d], hi, lo);
      hi8[j] = (short)hi; lo8[j] = (short)lo;
    }
    unsigned short* base = wpre + (size_t)((z * 8 + h) * 2 + fh) * 16384;
    *(short8*)(base + L * 8) = hi8;
    *(short8*)(base + 8192 + L * 8) = lo8;
  } else if (id < 51200) {       // Wg: 2 fh * 1024 chunks
    const int t = id - 49152;
    const int fh = t >> 10, L = t & 1023;
    const int d = L >> 3, m = L & 7;
    const int kk0 = (m ^ (d & 7)) << 3;
    short8 hi8, lo8;
#pragma unroll
    for (int j = 0; j < 8; j++) {
      unsigned short hi, lo;
      split2(Wg[d * DDIM + fh * 64 + kk0 + j], hi, lo);
      hi8[j] = (short)hi; lo8[j] = (short)lo;
    }
    unsigned short* base = wgpre + fh * 16384;
    *(short8*)(base + L * 8) = hi8;
    *(short8*)(base + 8192 + L * 8) = lo8;
  } else if (id < 116736) {      // x: 65536 chunks of 8
    const int t = id - 51200;
    const float* src = x + (size_t)t * 8;
    float4 v0 = *(const float4*)src, v1 = *(const float4*)(src + 4);
    float xv[8] = {v0.x, v0.y, v0.z, v0.w, v1.x, v1.y, v1.z, v1.w};
    short8 hi8, lo8;
#pragma unroll
    for (int j = 0; j < 8; j++) {
      unsigned short hi, lo; split2(xv[j], hi, lo);
      hi8[j] = (short)hi; lo8[j] = (short)lo;
    }
    *(short8*)(xh + (size_t)t * 8) = hi8;
    *(short8*)(xl + (size_t)t * 8) = lo8;
  }
}

// ---------------------------------------------------------------------------
// Kernel 1: k = x@Wk[h], v = x@Wv[h], q = x@Wq[h]*log2e — from pre-split
// inputs.  W staged via global_load_lds (no VALU), x frags loaded as short8.
// k/v: fp16 outputs in MFMA fragment order with bank swizzle baked in.
// q: row-major fp16 (== 16x16x32 A-frag order), pre-scaled by log2(e).
// 3-term bf16 MFMA. grid (16, NHEAD, 3): four 64-row tiles per block.
// ---------------------------------------------------------------------------
__global__ __launch_bounds__(256, 2) void proj_kernel(
    const unsigned short* __restrict__ xh, const unsigned short* __restrict__ xl,
    const unsigned short* __restrict__ wpre,
    _Float16* __restrict__ kfo, _Float16* __restrict__ vfo,
    _Float16* __restrict__ qfo)
{
  __shared__ alignas(16) unsigned short whi[8192];
  __shared__ alignas(16) unsigned short wlo[8192];
  const int tid = threadIdx.x, lane = tid & 63, wave = tid >> 6;
  const int l4 = lane & 15, quad = lane >> 4;
  const int h = blockIdx.y, z = blockIdx.z;
  const unsigned short* wb = wpre + (size_t)((z * 8 + h) * 2) * 16384;

  floatx4 acc[4][8];
#pragma unroll
  for (int t4 = 0; t4 < 4; t4++)
#pragma unroll
    for (int c = 0; c < 8; c++) acc[t4][c] = (floatx4)0.f;

  for (int fh = 0; fh < 2; fh++) {
    {
      const unsigned short* src = wb + fh * 16384;
      const unsigned short* sh = src + wave * 2048 + lane * 8;
      const unsigned short* sl = src + 8192 + wave * 2048 + lane * 8;
      unsigned short* dh = &whi[wave * 2048];
      unsigned short* dl = &wlo[wave * 2048];
#pragma unroll
      for (int it = 0; it < 4; it++) {
        async_cp16(sh + it * 512, dh + it * 512);
        async_cp16(sl + it * 512, dl + it * 512);
      }
    }
    __syncthreads();  // compiler drains vmcnt before barrier

#pragma unroll
    for (int t4 = 0; t4 < 4; t4++) {
      const int row = blockIdx.x * 256 + t4 * 64 + wave * 16 + l4;
      const size_t xo = (size_t)row * DDIM + fh * 64 + quad * 8;
      short8 ah[2], al[2];
      ah[0] = *(const short8*)(xh + xo);
      ah[1] = *(const short8*)(xh + xo + 32);
      al[0] = *(const short8*)(xl + xo);
      al[1] = *(const short8*)(xl + xo + 32);
#pragma unroll
      for (int t2 = 0; t2 < 2; t2++) {
#pragma unroll
        for (int c = 0; c < 8; c++) {
          const int col = c * 16 + l4;
          const int idx = (col * 8 + ((t2 * 4 + quad) ^ (col & 7))) * 8;
          short8 bh = *(const short8*)&whi[idx];
          short8 bl = *(const short8*)&wlo[idx];
          acc[t4][c] = __builtin_amdgcn_mfma_f32_16x16x32_bf16(ah[t2], bh, acc[t4][c], 0, 0, 0);
          acc[t4][c] = __builtin_amdgcn_mfma_f32_16x16x32_bf16(al[t2], bh, acc[t4][c], 0, 0, 0);
          acc[t4][c] = __builtin_amdgcn_mfma_f32_16x16x32_bf16(ah[t2], bl, acc[t4][c], 0, 0, 0);
        }
      }
    }
    __syncthreads();
  }

  const int rb = wave * 16 + quad * 4;
#pragma unroll
  for (int t4 = 0; t4 < 4; t4++) {
    const int tile = blockIdx.x * 4 + t4;
    const size_t tilebase = (size_t)(h * 64 + tile) * 8192;
#pragma unroll
    for (int c = 0; c < 8; c++) {
      const int d = c * 16 + l4;
#pragma unroll
      for (int r = 0; r < 4; r++) {
        const int kl = rb + r;
        const float val = acc[t4][c][r];
        if (z == 0) {
          const int c2 = kl >> 4, l4k = kl & 15;
          const int tt = d >> 5, qd = (d >> 3) & 3, jj = d & 7;
          const int qX = qd ^ ((l4k >> 1) & 3);
          kfo[tilebase + (size_t)((c2 * 4 + tt) * 16 + l4k) * 32 + qX * 8 + jj] =
              (_Float16)val;
        } else if (z == 1) {
          const int c2 = d >> 4, l4v = d & 15;
          const int tt = kl >> 5, qd = (kl >> 3) & 3, jj = kl & 7;
          const int qX = qd ^ ((l4v >> 1) & 3);
          vfo[tilebase + (size_t)((c2 * 2 + tt) * 16 + l4v) * 32 + qX * 8 + jj] =
              (_Float16)val;
        } else {
          // q: row-major fp16, scaled by log2(e) for base-2 softmax
          qfo[((size_t)h * NROWS + (size_t)tile * 64 + kl) * DDIM + d] =
              (_Float16)(val * LOG2E);
        }
      }
    }
  }
}

// ---------------------------------------------------------------------------
// Kernel 2: flash attention, SOFTWARE-PIPELINED. 64 q-rows/block, SPLIT-K x3.
// grid 1536 = 2 * (3 blocks/CU * 256 CU): two full residency passes, no tail.
// Iteration kt:  Vload(kt) -> softmax(S(kt)) [DPP row-max, no lgkm] ->
//   Pstore -> rescale -> barrier -> prefetch K(kt+2) -> ISSUE QK(kt+1) ->
//   PV(kt).  QK(kt+1) results are consumed by NEXT iter's softmax, so the
//   softmax VALU chain runs while the matrix pipe drains QK+PV — the two
//   pipes overlap instead of alternating (round-4: 22% mfma + 35% valu,
//   43% stall on the serial chain).
// Hazards: barrier drains each wave's K-prefetch (one full iter in flight)
// and V-loads; k[cur] overwritten only after the barrier that follows its
// last ds_reads (QK issued pre-barrier); P tile is wave-private (same-wave
// in-order DS).  __launch_bounds__(256,3): ~168-reg cap, est. peak ~130.
// ---------------------------------------------------------------------------
struct FlashLds {
  _Float16 k[2][8192];  // 32768 B
  _Float16 p[4][1024];  // 8192 B, wave-private P tile [kblk8][qrow16][8]
};

__global__ __launch_bounds__(256, 3) void flash_kernel(
    const _Float16* __restrict__ qfo, const _Float16* __restrict__ kfo,
    const _Float16* __restrict__ vfo,
    _Float16* __restrict__ op, float* __restrict__ mb, float* __restrict__ lb)
{
  __shared__ alignas(16) FlashLds lds;
  const int tid = threadIdx.x, lane = tid & 63, wave = tid >> 6;
  const int l4 = lane & 15, quad = lane >> 4;
  const int h = blockIdx.x & 7, qt = (blockIdx.x >> 3) & 63, s = blockIdx.x >> 9;
  const int q0 = qt * 64;

  // Q A-frags: row-major fp16 IS the 16x16x32 A layout (row=l4, k=quad*8+j)
  half8 aq[4];
  {
    const _Float16* qr =
        qfo + ((size_t)h * NROWS + q0 + wave * 16 + l4) * DDIM + quad * 8;
#pragma unroll
    for (int t = 0; t < 4; t++) aq[t] = *(const half8*)(qr + t * 32);
  }

  float m_run[4];
#pragma unroll
  for (int r = 0; r < 4; r++) m_run[r] = -1e30f;
  floatx4 Oacc[8], lacc = (floatx4)0.f;
#pragma unroll
  for (int c = 0; c < 8; c++) Oacc[c] = (floatx4)0.f;

  half8 vones;
#pragma unroll
  for (int j = 0; j < 8; j++) vones[j] = (_Float16)1.f;

  const _Float16* kfo_h = kfo + (size_t)h * 64 * 8192;
  const _Float16* vfo_h = vfo + (size_t)h * 64 * 8192;
  const int lq = (l4 * 4 + (quad ^ ((l4 >> 1) & 3))) * 8;
  const int kt0 = (s == 0) ? 0 : (s == 1 ? 22 : 43);
  const int kt1 = (s == 0) ? 22 : (s == 1 ? 43 : 64);

  // ---- prologue: stage K(kt0), prefetch K(kt0+1), issue QK(kt0) ----
  {
    const _Float16* ks = kfo_h + (size_t)kt0 * 8192 + wave * 2048 + lane * 8;
    _Float16* kd = &lds.k[kt0 & 1][wave * 2048];
#pragma unroll
    for (int it = 0; it < 4; it++) async_cp16(ks + it * 512, kd + it * 512);
  }
  __syncthreads();
  if (kt0 + 1 < kt1) {
    const _Float16* ks = kfo_h + (size_t)(kt0 + 1) * 8192 + wave * 2048 + lane * 8;
    _Float16* kd = &lds.k[(kt0 + 1) & 1][wave * 2048];
#pragma unroll
    for (int it = 0; it < 4; it++) async_cp16(ks + it * 512, kd + it * 512);
  }

  floatx4 Sc[4];
#pragma unroll
  for (int c = 0; c < 4; c++) Sc[c] = (floatx4)0.f;
#pragma unroll
  for (int t = 0; t < 4; t++) {
    half8 b[4];
#pragma unroll
    for (int c = 0; c < 4; c++)
      b[c] = *(const half8*)&lds.k[kt0 & 1][(c * 4 + t) * 512 + lq];
#pragma unroll
    for (int c = 0; c < 4; c++)
      Sc[c] = __builtin_amdgcn_mfma_f32_16x16x32_f16(aq[t], b[c], Sc[c], 0, 0, 0);
  }

  for (int kt = kt0; kt < kt1; ++kt) {
    const int cur = kt & 1;

    // ---- V frags for THIS tile: issue first, consumed at PV (full cover) ----
    half8 vfrag[8][2];
    {
      const _Float16* vtb = vfo_h + (size_t)kt * 8192;
#pragma unroll
      for (int c = 0; c < 8; c++)
#pragma unroll
        for (int t = 0; t < 2; t++)
          vfrag[c][t] = *(const half8*)(vtb + (c * 2 + t) * 512 + lq);
    }

    // ---- softmax on Sc = S(kt), base-2; DPP row-max (VALU-only) ----
    float alpha[4];
    {
      float mt[4];
#pragma unroll
      for (int r = 0; r < 4; r++)
        mt[r] = fmaxf(fmaxf(Sc[0][r], Sc[1][r]), fmaxf(Sc[2][r], Sc[3][r]));
#pragma unroll
      for (int r = 0; r < 4; r++) mt[r] = dpp_max16(mt[r]);
#pragma unroll
      for (int r = 0; r < 4; r++) {
        const float mn = fmaxf(m_run[r], mt[r]);
        alpha[r] = __ocml_native_exp2_f32(m_run[r] - mn);
        m_run[r] = mn;
      }
#pragma unroll
      for (int r = 0; r < 4; r++)
#pragma unroll
        for (int c = 0; c < 4; c++)
          Sc[c][r] = __ocml_native_exp2_f32(Sc[c][r] - m_run[r]);
    }

    // ---- P: C-layout -> A-layout via wave-private frag-ordered LDS ----
#pragma unroll
    for (int c = 0; c < 4; c++)
#pragma unroll
      for (int r = 0; r < 4; r++)
        lds.p[wave][((c * 2 + (l4 >> 3)) * 16 + quad * 4 + r) * 8 + (l4 & 7)] =
            (_Float16)Sc[c][r];

    // ---- rescale O/l only when the running max moved ----
    {
      const bool moved = (alpha[0] != 1.f) | (alpha[1] != 1.f) |
                         (alpha[2] != 1.f) | (alpha[3] != 1.f);
      if (__any(moved)) {
#pragma unroll
        for (int c = 0; c < 8; c++) {
          Oacc[c][0] *= alpha[0]; Oacc[c][1] *= alpha[1];
          Oacc[c][2] *= alpha[2]; Oacc[c][3] *= alpha[3];
        }
        lacc[0] *= alpha[0]; lacc[1] *= alpha[1];
        lacc[2] *= alpha[2]; lacc[3] *= alpha[3];
      }
    }

    // ---- barrier: K(kt+1) staged; all reads of k[cur] drained ----
    __syncthreads();

    // ---- prefetch K(kt+2) into k[cur] (free after the barrier) ----
    if (kt + 2 < kt1) {
      const _Float16* ks = kfo_h + (size_t)(kt + 2) * 8192 + wave * 2048 + lane * 8;
      _Float16* kd = &lds.k[cur][wave * 2048];
#pragma unroll
      for (int it = 0; it < 4; it++) async_cp16(ks + it * 512, kd + it * 512);
    }

    __builtin_amdgcn_s_setprio(1);
    // ---- ISSUE QK(kt+1) from k[cur^1]; results consumed next iteration ----
    floatx4 Sn[4];
    if (kt + 1 < kt1) {
#pragma unroll
      for (int c = 0; c < 4; c++) Sn[c] = (floatx4)0.f;
#pragma unroll
      for (int t = 0; t < 4; t++) {
        half8 b[4];
#pragma unroll
        for (int c = 0; c < 4; c++)
          b[c] = *(const half8*)&lds.k[cur ^ 1][(c * 4 + t) * 512 + lq];
#pragma unroll
        for (int c = 0; c < 4; c++)
          Sn[c] = __builtin_amdgcn_mfma_f32_16x16x32_f16(aq[t], b[c], Sn[c], 0, 0, 0);
      }
    }

    // ---- O += P@V (V from registers), l += P@ones ----
#pragma unroll
    for (int t = 0; t < 2; t++) {
      half8 ap = *(const half8*)&lds.p[wave][((t * 4 + quad) * 16 + l4) * 8];
      lacc = __builtin_amdgcn_mfma_f32_16x16x32_f16(ap, vones, lacc, 0, 0, 0);
#pragma unroll
      for (int c = 0; c < 8; c++)
        Oacc[c] = __builtin_amdgcn_mfma_f32_16x16x32_f16(ap, vfrag[c][t], Oacc[c], 0, 0, 0);
    }
    __builtin_amdgcn_s_setprio(0);

    if (kt + 1 < kt1) {
#pragma unroll
      for (int c = 0; c < 4; c++) Sc[c] = Sn[c];
    }
  }

  // ---- epilogue: unnormalized partial O (fp16) + per-row (m, l) ----
  const int rbase = wave * 16 + quad * 4;
  const size_t rowbase = (size_t)(s * NHEAD + h) * NROWS + q0 + rbase;
#pragma unroll
  for (int c = 0; c < 8; c++) {
    const int col = c * 16 + l4;
#pragma unroll
    for (int r = 0; r < 4; r++)
      op[(rowbase + r) * DDIM + col] = (_Float16)Oacc[c][r];
  }
  if (l4 == 0) {
#pragma unroll
    for (int r = 0; r < 4; r++) {
      mb[rowbase + r] = m_run[r];
      lb[rowbase + r] = lacc[r];
    }
  }
}

// ---------------------------------------------------------------------------
// Kernel 3: merge 3 split-K partials + head-sum -> u. grid 4096, block 128.
// m values are in base-2 units -> exp2 here.
// ---------------------------------------------------------------------------
__global__ __launch_bounds__(128) void merge_kernel(
    const _Float16* __restrict__ op, const float* __restrict__ mb,
    const float* __restrict__ lb, const float* __restrict__ Wm,
    float* __restrict__ u)
{
  __shared__ float sc[3][NHEAD];
  const int n = blockIdx.x, d = threadIdx.x;
  if (d < NHEAD) {
    const int h = d;
    float m0 = mb[(size_t)(0 * NHEAD + h) * NROWS + n];
    float m1 = mb[(size_t)(1 * NHEAD + h) * NROWS + n];
    float m2 = mb[(size_t)(2 * NHEAD + h) * NROWS + n];
    float l0 = lb[(size_t)(0 * NHEAD + h) * NROWS + n];
    float l1 = lb[(size_t)(1 * NHEAD + h) * NROWS + n];
    float l2 = lb[(size_t)(2 * NHEAD + h) * NROWS + n];
    const float m = fmaxf(fmaxf(m0, m1), m2);
    const float a0 = __ocml_native_exp2_f32(m0 - m);
    const float a1 = __ocml_native_exp2_f32(m1 - m);
    const float a2 = __ocml_native_exp2_f32(m2 - m);
    const float invL = Wm[h] / (l0 * a0 + l1 * a1 + l2 * a2);
    sc[0][h] = a0 * invL;
    sc[1][h] = a1 * invL;
    sc[2][h] = a2 * invL;
  }
  __syncthreads();
  float acc = 0.f;
#pragma unroll
  for (int s = 0; s < 3; s++)
#pragma unroll
    for (int h = 0; h < NHEAD; h++)
      acc += sc[s][h] * (float)op[((size_t)(s * NHEAD + h) * NROWS + n) * DDIM + d];
  u[(size_t)n * DDIM + d] = acc;
}

// ---------------------------------------------------------------------------
// Kernel 4: y = x + relu((x+u) @ Wg^T + bg), 3-term bf16 MFMA.
// Wg pre-split: staged via global_load_lds (no VALU).  grid 64, block 256.
// ---------------------------------------------------------------------------
__global__ __launch_bounds__(256, 2) void mlp_kernel(
    const float* __restrict__ x, const float* __restrict__ u,
    const unsigned short* __restrict__ wgpre, const float* __restrict__ bg,
    float* __restrict__ out)
{
  __shared__ alignas(16) unsigned short whi[8192];
  __shared__ alignas(16) unsigned short wlo[8192];
  const int tid = threadIdx.x, lane = tid & 63, wave = tid >> 6;
  const int l4 = lane & 15, quad = lane >> 4;
  const int r0 = blockIdx.x * 64;

  floatx4 acc[8];
#pragma unroll
  for (int c = 0; c < 8; c++) acc[c] = (floatx4)0.f;

  for (int fh = 0; fh < 2; fh++) {
    {
      const unsigned short* src = wgpre + fh * 16384;
      const unsigned short* sh = src + wave * 2048 + lane * 8;
      const unsigned short* sl = src + 8192 + wave * 2048 + lane * 8;
      unsigned short* dh = &whi[wave * 2048];
      unsigned short* dl = &wlo[wave * 2048];
#pragma unroll
      for (int it = 0; it < 4; it++) {
        async_cp16(sh + it * 512, dh + it * 512);
        async_cp16(sl + it * 512, dl + it * 512);
      }
    }
    __syncthreads();

    const size_t xoff = (size_t)(r0 + wave * 16 + l4) * DDIM + fh * 64 + quad * 8;
    short8 ah[2], al[2];
#pragma unroll
    for (int t2 = 0; t2 < 2; t2++) {
      float4 x0 = *(const float4*)(x + xoff + t2 * 32);
      float4 x1 = *(const float4*)(x + xoff + t2 * 32 + 4);
      float4 u0 = *(const float4*)(u + xoff + t2 * 32);
      float4 u1 = *(const float4*)(u + xoff + t2 * 32 + 4);
      float hv[8] = {x0.x + u0.x, x0.y + u0.y, x0.z + u0.z, x0.w + u0.w,
                     x1.x + u1.x, x1.y + u1.y, x1.z + u1.z, x1.w + u1.w};
#pragma unroll
      for (int j = 0; j < 8; j++) {
        unsigned short hi, lo; split2(hv[j], hi, lo);
        ah[t2][j] = (short)hi; al[t2][j] = (short)lo;
      }
    }
#pragma unroll
    for (int t2 = 0; t2 < 2; t2++) {
#pragma unroll
      for (int c = 0; c < 8; c++) {
        const int col = c * 16 + l4;
        const int idx = (col * 8 + ((t2 * 4 + quad) ^ (col & 7))) * 8;
        short8 bh = *(const short8*)&whi[idx];
        short8 bl = *(const short8*)&wlo[idx];
        acc[c] = __builtin_amdgcn_mfma_f32_16x16x32_bf16(ah[t2], bh, acc[c], 0, 0, 0);
        acc[c] = __builtin_amdgcn_mfma_f32_16x16x32_bf16(al[t2], bh, acc[c], 0, 0, 0);
        acc[c] = __builtin_amdgcn_mfma_f32_16x16x32_bf16(ah[t2], bl, acc[c], 0, 0, 0);
      }
    }
    __syncthreads();
  }

  const int rbase = wave * 16 + quad * 4;
#pragma unroll
  for (int c = 0; c < 8; c++) {
    const int col = c * 16 + l4;
    const float bgf = bg[col];
#pragma unroll
    for (int r = 0; r < 4; r++) {
      const size_t idx = (size_t)(r0 + rbase + r) * DDIM + col;
      out[idx] = x[idx] + fmaxf(acc[c][r] + bgf, 0.f);
    }
  }
}

extern "C" void kernel_launch(void* const* d_in, const int* in_sizes, int n_in,
                              void* d_out, int out_size, void* d_ws, size_t ws_size,
                              hipStream_t stream) {
  float* out = (float*)d_out;
  const int fill_blocks = (out_size + 255) / 256;

  const bool ok_sizes =
      n_in == 7 &&
      in_sizes[0] == NROWS * DDIM &&
      in_sizes[1] == NHEAD * DDIM * DDIM &&
      in_sizes[2] == NHEAD * DDIM * DDIM &&
      in_sizes[3] == NHEAD * DDIM * DDIM &&
      in_sizes[4] == NHEAD &&
      in_sizes[5] == DDIM * DDIM &&
      in_sizes[6] == DDIM &&
      out_size == NROWS * DDIM;
  if (!ok_sizes) {
    fill_kernel<<<fill_blocks, 256, 0, stream>>>(out, 1000.f, out_size);
    return;
  }

  // ws: u 2MB + k/v/qfo 25.2 + op(3) 25.2 + mb/lb 0.8 + wpre 1.5 + wgpre 0.06
  //     + xh/xl 2.1  = ~57 MB
  const size_t HND = (size_t)NHEAD * NROWS * DDIM;
  const size_t ND  = (size_t)NROWS * DDIM;
  const size_t WPRE_N  = (size_t)3 * 8 * 2 * 16384;  // ushorts
  const size_t WGPRE_N = (size_t)2 * 16384;
  const size_t need = ND * 4 + 3 * HND * 2 + 3 * HND * 2 +
                      2 * (3 * (size_t)NHEAD * NROWS) * 4 +
                      (WPRE_N + WGPRE_N + 2 * ND) * 2;
  if (ws_size < need) {
    fill_kernel<<<fill_blocks, 256, 0, stream>>>(out, 500.f, out_size);
    return;
  }

  const float* x  = (const float*)d_in[0];
  const float* Wk = (const float*)d_in[1];
  const float* Wq = (const float*)d_in[2];
  const float* Wv = (const float*)d_in[3];
  const float* Wm = (const float*)d_in[4];
  const float* Wg = (const float*)d_in[5];
  const float* bg = (const float*)d_in[6];

  float*          u     = (float*)d_ws;
  _Float16*       kfo   = (_Float16*)(u + ND);
  _Float16*       vfo   = kfo + HND;
  _Float16*       qfo   = vfo + HND;
  _Float16*       op    = qfo + HND;                 // 3*HND
  float*          mb    = (float*)(op + 3 * HND);    // 3*NHEAD*NROWS
  float*          lb    = mb + 3 * NHEAD * NROWS;
  unsigned short* wpre  = (unsigned short*)(lb + 3 * NHEAD * NROWS);
  unsigned short* wgpre = wpre + WPRE_N;
  unsigned short* xh    = wgpre + WGPRE_N;
  unsigned short* xl    = xh + ND;

  (void)hipGetLastError();
  prep_kernel<<<dim3(456), 256, 0, stream>>>(Wk, Wv, Wq, Wg, x, wpre, wgpre, xh, xl);
  proj_kernel<<<dim3(16, NHEAD, 3), 256, 0, stream>>>(xh, xl, wpre, kfo, vfo, qfo);
  flash_kernel<<<dim3(1536), 256, 0, stream>>>(qfo, kfo, vfo, op, mb, lb);
  merge_kernel<<<dim3(4096), 128, 0, stream>>>(op, mb, lb, Wm, u);
  mlp_kernel<<<dim3(64), 256, 0, stream>>>(x, u, wgpre, bg, out);
  if (hipGetLastError() != hipSuccess) {
    fill_kernel<<<fill_blocks, 256, 0, stream>>>(out, 2000.f, out_size);
  }
}

// Round 6
// 215.217 us; speedup vs baseline: 1.8067x; 1.0767x over previous
//
#include <hip/hip_runtime.h>

#define NROWS 4096
#define DDIM  128
#define NHEAD 8
#define LOG2E 1.44269504088896f

// native 2^x  ->  single v_exp_f32 (ocml symbol always present in device libs)
extern "C" __device__ float __ocml_native_exp2_f32(float);

typedef __attribute__((ext_vector_type(8))) short    short8;
typedef __attribute__((ext_vector_type(8))) _Float16 half8;
typedef __attribute__((ext_vector_type(4))) float    floatx4;

__device__ __forceinline__ float bf2f(unsigned short u){
  unsigned v = ((unsigned)u) << 16;
  return __builtin_bit_cast(float, v);
}
__device__ __forceinline__ unsigned short f2bf(float f){
  unsigned u = __builtin_bit_cast(unsigned, f);
  u += 0x7FFFu + ((u >> 16) & 1u);
  return (unsigned short)(u >> 16);
}
__device__ __forceinline__ void split2(float v, unsigned short& hi, unsigned short& lo){
  hi = f2bf(v);
  lo = f2bf(v - bf2f(hi));
}
// async global->LDS, 16B per lane: LDS dest = wave-uniform base + lane*16.
__device__ __forceinline__ void async_cp16(const void* g, void* l){
  __builtin_amdgcn_global_load_lds(
      (const __attribute__((address_space(1))) void*)g,
      (__attribute__((address_space(3))) void*)l, 16, 0, 0);
}
// 16-lane (DPP row) max reduce via row_ror 8/4/2/1 — pure VALU, no lgkm.
__device__ __forceinline__ float dpp_max16(float v){
  int t;
  t = __builtin_amdgcn_update_dpp(0, __builtin_bit_cast(int, v), 0x128, 0xF, 0xF, false);
  v = fmaxf(v, __builtin_bit_cast(float, t));
  t = __builtin_amdgcn_update_dpp(0, __builtin_bit_cast(int, v), 0x124, 0xF, 0xF, false);
  v = fmaxf(v, __builtin_bit_cast(float, t));
  t = __builtin_amdgcn_update_dpp(0, __builtin_bit_cast(int, v), 0x122, 0xF, 0xF, false);
  v = fmaxf(v, __builtin_bit_cast(float, t));
  t = __builtin_amdgcn_update_dpp(0, __builtin_bit_cast(int, v), 0x121, 0xF, 0xF, false);
  v = fmaxf(v, __builtin_bit_cast(float, t));
  return v;
}

// fp32 sentinels: 500=ws too small, 1000=in_sizes mismatch, 2000=launch fail.
__global__ void fill_kernel(float* __restrict__ out, float val, int n){
  int i = blockIdx.x * 256 + threadIdx.x;
  if (i < n) out[i] = val;
}

// ---------------------------------------------------------------------------
// Kernel 0: prep — one-time bf16 hi/lo splits so proj/mlp do ZERO split2 VALU.
// W tiles stored in LDS-LINEAR chunk order with XOR swizzle baked in:
//   chunk L = d*8+m  holds  T[d][(m^(d&7))*8 + j],  j=0..7
//   proj T[d][k] = W[(fh*64+k)*128 + d] (W^T tile);  mlp T[d][k]=Wg[d*128+fh*64+k]
// Readers use idx = (col*8 + (k8 ^ (col&7)))*8.
// x split to xh/xl row-major bf16 (direct short8 A-frag loads).
// ---------------------------------------------------------------------------
__global__ __launch_bounds__(256) void prep_kernel(
    const float* __restrict__ Wk, const float* __restrict__ Wv,
    const float* __restrict__ Wq, const float* __restrict__ Wg,
    const float* __restrict__ x,
    unsigned short* __restrict__ wpre, unsigned short* __restrict__ wgpre,
    unsigned short* __restrict__ xh, unsigned short* __restrict__ xl)
{
  const int id = blockIdx.x * 256 + threadIdx.x;
  if (id < 49152) {              // W_k/v/q: 3 z * 8 h * 2 fh * 1024 chunks
    const int z = id >> 14, rem = id & 16383;
    const int h = rem >> 11, rem2 = rem & 2047;
    const int fh = rem2 >> 10, L = rem2 & 1023;
    const int d = L >> 3, m = L & 7;
    const int kk0 = (m ^ (d & 7)) << 3;
    const float* W = (z == 0 ? Wk : (z == 1 ? Wv : Wq)) + h * DDIM * DDIM;
    short8 hi8, lo8;
#pragma unroll
    for (int j = 0; j < 8; j++) {
      unsigned short hi, lo;
      split2(W[(fh * 64 + kk0 + j) * DDIM + d], hi, lo);
      hi8[j] = (short)hi; lo8[j] = (short)lo;
    }
    unsigned short* base = wpre + (size_t)((z * 8 + h) * 2 + fh) * 16384;
    *(short8*)(base + L * 8) = hi8;
    *(short8*)(base + 8192 + L * 8) = lo8;
  } else if (id < 51200) {       // Wg: 2 fh * 1024 chunks
    const int t = id - 49152;
    const int fh = t >> 10, L = t & 1023;
    const int d = L >> 3, m = L & 7;
    const int kk0 = (m ^ (d & 7)) << 3;
    short8 hi8, lo8;
#pragma unroll
    for (int j = 0; j < 8; j++) {
      unsigned short hi, lo;
      split2(Wg[d * DDIM + fh * 64 + kk0 + j], hi, lo);
      hi8[j] = (short)hi; lo8[j] = (short)lo;
    }
    unsigned short* base = wgpre + fh * 16384;
    *(short8*)(base + L * 8) = hi8;
    *(short8*)(base + 8192 + L * 8) = lo8;
  } else if (id < 116736) {      // x: 65536 chunks of 8
    const int t = id - 51200;
    const float* src = x + (size_t)t * 8;
    float4 v0 = *(const float4*)src, v1 = *(const float4*)(src + 4);
    float xv[8] = {v0.x, v0.y, v0.z, v0.w, v1.x, v1.y, v1.z, v1.w};
    short8 hi8, lo8;
#pragma unroll
    for (int j = 0; j < 8; j++) {
      unsigned short hi, lo; split2(xv[j], hi, lo);
      hi8[j] = (short)hi; lo8[j] = (short)lo;
    }
    *(short8*)(xh + (size_t)t * 8) = hi8;
    *(short8*)(xl + (size_t)t * 8) = lo8;
  }
}

// ---------------------------------------------------------------------------
// Kernel 1: k = x@Wk[h], v = x@Wv[h], q = x@Wq[h]*log2e — from pre-split
// inputs.  W staged via global_load_lds (no VALU), x frags loaded as short8.
// k/v: fp16 outputs in MFMA fragment order with bank swizzle baked in.
// q: row-major fp16 (== 16x16x32 A-frag order), pre-scaled by log2(e).
// 3-term bf16 MFMA. grid (16, NHEAD, 3): four 64-row tiles per block.
// ---------------------------------------------------------------------------
__global__ __launch_bounds__(256, 2) void proj_kernel(
    const unsigned short* __restrict__ xh, const unsigned short* __restrict__ xl,
    const unsigned short* __restrict__ wpre,
    _Float16* __restrict__ kfo, _Float16* __restrict__ vfo,
    _Float16* __restrict__ qfo)
{
  __shared__ alignas(16) unsigned short whi[8192];
  __shared__ alignas(16) unsigned short wlo[8192];
  const int tid = threadIdx.x, lane = tid & 63, wave = tid >> 6;
  const int l4 = lane & 15, quad = lane >> 4;
  const int h = blockIdx.y, z = blockIdx.z;
  const unsigned short* wb = wpre + (size_t)((z * 8 + h) * 2) * 16384;

  floatx4 acc[4][8];
#pragma unroll
  for (int t4 = 0; t4 < 4; t4++)
#pragma unroll
    for (int c = 0; c < 8; c++) acc[t4][c] = (floatx4)0.f;

  for (int fh = 0; fh < 2; fh++) {
    {
      const unsigned short* src = wb + fh * 16384;
      const unsigned short* sh = src + wave * 2048 + lane * 8;
      const unsigned short* sl = src + 8192 + wave * 2048 + lane * 8;
      unsigned short* dh = &whi[wave * 2048];
      unsigned short* dl = &wlo[wave * 2048];
#pragma unroll
      for (int it = 0; it < 4; it++) {
        async_cp16(sh + it * 512, dh + it * 512);
        async_cp16(sl + it * 512, dl + it * 512);
      }
    }
    __syncthreads();  // compiler drains vmcnt before barrier

#pragma unroll
    for (int t4 = 0; t4 < 4; t4++) {
      const int row = blockIdx.x * 256 + t4 * 64 + wave * 16 + l4;
      const size_t xo = (size_t)row * DDIM + fh * 64 + quad * 8;
      short8 ah[2], al[2];
      ah[0] = *(const short8*)(xh + xo);
      ah[1] = *(const short8*)(xh + xo + 32);
      al[0] = *(const short8*)(xl + xo);
      al[1] = *(const short8*)(xl + xo + 32);
#pragma unroll
      for (int t2 = 0; t2 < 2; t2++) {
#pragma unroll
        for (int c = 0; c < 8; c++) {
          const int col = c * 16 + l4;
          const int idx = (col * 8 + ((t2 * 4 + quad) ^ (col & 7))) * 8;
          short8 bh = *(const short8*)&whi[idx];
          short8 bl = *(const short8*)&wlo[idx];
          acc[t4][c] = __builtin_amdgcn_mfma_f32_16x16x32_bf16(ah[t2], bh, acc[t4][c], 0, 0, 0);
          acc[t4][c] = __builtin_amdgcn_mfma_f32_16x16x32_bf16(al[t2], bh, acc[t4][c], 0, 0, 0);
          acc[t4][c] = __builtin_amdgcn_mfma_f32_16x16x32_bf16(ah[t2], bl, acc[t4][c], 0, 0, 0);
        }
      }
    }
    __syncthreads();
  }

  const int rb = wave * 16 + quad * 4;
#pragma unroll
  for (int t4 = 0; t4 < 4; t4++) {
    const int tile = blockIdx.x * 4 + t4;
    const size_t tilebase = (size_t)(h * 64 + tile) * 8192;
#pragma unroll
    for (int c = 0; c < 8; c++) {
      const int d = c * 16 + l4;
#pragma unroll
      for (int r = 0; r < 4; r++) {
        const int kl = rb + r;
        const float val = acc[t4][c][r];
        if (z == 0) {
          const int c2 = kl >> 4, l4k = kl & 15;
          const int tt = d >> 5, qd = (d >> 3) & 3, jj = d & 7;
          const int qX = qd ^ ((l4k >> 1) & 3);
          kfo[tilebase + (size_t)((c2 * 4 + tt) * 16 + l4k) * 32 + qX * 8 + jj] =
              (_Float16)val;
        } else if (z == 1) {
          const int c2 = d >> 4, l4v = d & 15;
          const int tt = kl >> 5, qd = (kl >> 3) & 3, jj = kl & 7;
          const int qX = qd ^ ((l4v >> 1) & 3);
          vfo[tilebase + (size_t)((c2 * 2 + tt) * 16 + l4v) * 32 + qX * 8 + jj] =
              (_Float16)val;
        } else {
          // q: row-major fp16, scaled by log2(e) for base-2 softmax
          qfo[((size_t)h * NROWS + (size_t)tile * 64 + kl) * DDIM + d] =
              (_Float16)(val * LOG2E);
        }
      }
    }
  }
}

// ---------------------------------------------------------------------------
// Kernel 2: flash attention. 64 q-rows/block, SPLIT-K x2.
// grid 1024: h=bid&7 (XCD-affine), qt=(bid>>3)&63, s=bid>>9.
// LDS 40960 B * 4 = 163840 B = the whole CU -> 4 blocks/CU; grid 1024 =
// 4 * 256 CUs exactly: ONE full-residency pass, no tail, 4 waves/SIMD.
// __launch_bounds__(256,4) register budget 128 (unified arch+acc):
//   acc = Oacc 32 + lacc 4 = 36;  arch peak kept low by
//   (a) round-4 skeleton (no QK-ahead pipeline — measured null, cost regs),
//   (b) PV t-SPLIT: only 8 V-frags (32 regs) live at a time,
//   (c) rescale BEFORE V-loads (alpha dead before vfrag lives).
//   Round-4 skeleton measured 80 arch at (256,3); this body is smaller.
// DPP row-max (row_ror 8/4/2/1): pure-VALU 16-lane reduce, no lgkm waits.
// K double-buffered via global_load_lds, ONE barrier/iter; base-2 softmax.
// ---------------------------------------------------------------------------
struct FlashLds {
  _Float16 k[2][8192];  // 32768 B
  _Float16 p[4][1024];  // 8192 B, wave-private P tile [kblk8][qrow16][8]
};

__global__ __launch_bounds__(256, 4) void flash_kernel(
    const _Float16* __restrict__ qfo, const _Float16* __restrict__ kfo,
    const _Float16* __restrict__ vfo,
    _Float16* __restrict__ op, float* __restrict__ mb, float* __restrict__ lb)
{
  __shared__ alignas(16) FlashLds lds;
  const int tid = threadIdx.x, lane = tid & 63, wave = tid >> 6;
  const int l4 = lane & 15, quad = lane >> 4;
  const int h = blockIdx.x & 7, qt = (blockIdx.x >> 3) & 63, s = blockIdx.x >> 9;
  const int q0 = qt * 64;

  // Q A-frags: row-major fp16 IS the 16x16x32 A layout (row=l4, k=quad*8+j)
  half8 aq[4];
  {
    const _Float16* qr =
        qfo + ((size_t)h * NROWS + q0 + wave * 16 + l4) * DDIM + quad * 8;
#pragma unroll
    for (int t = 0; t < 4; t++) aq[t] = *(const half8*)(qr + t * 32);
  }

  float m_run[4];
#pragma unroll
  for (int r = 0; r < 4; r++) m_run[r] = -1e30f;
  floatx4 Oacc[8], lacc = (floatx4)0.f;
#pragma unroll
  for (int c = 0; c < 8; c++) Oacc[c] = (floatx4)0.f;

  half8 vones;
#pragma unroll
  for (int j = 0; j < 8; j++) vones[j] = (_Float16)1.f;

  const _Float16* kfo_h = kfo + (size_t)h * 64 * 8192;
  const _Float16* vfo_h = vfo + (size_t)h * 64 * 8192;
  const int lq = (l4 * 4 + (quad ^ ((l4 >> 1) & 3))) * 8;
  const int kt0 = s * 32, kt1 = kt0 + 32;

  // preload K(kt0) into buffer 0 (kt0 is even for both s)
  {
    const _Float16* ks = kfo_h + (size_t)kt0 * 8192 + wave * 2048 + lane * 8;
    _Float16* kd = &lds.k[0][wave * 2048];
#pragma unroll
    for (int it = 0; it < 4; it++) async_cp16(ks + it * 512, kd + it * 512);
  }

  for (int kt = kt0; kt < kt1; ++kt) {
    const int cur = kt & 1;
    __syncthreads();  // drains K(kt) copies; all waves done with k[cur^1]

    // ---- prefetch K(kt+1) into the other buffer ----
    if (kt + 1 < kt1) {
      const _Float16* ks = kfo_h + (size_t)(kt + 1) * 8192 + wave * 2048 + lane * 8;
      _Float16* kd = &lds.k[cur ^ 1][wave * 2048];
#pragma unroll
      for (int it = 0; it < 4; it++) async_cp16(ks + it * 512, kd + it * 512);
    }

    // ---- S = Q @ K^T (K from LDS buffer cur); S is in base-2 units ----
    floatx4 Sf[4];
#pragma unroll
    for (int c = 0; c < 4; c++) Sf[c] = (floatx4)0.f;
    __builtin_amdgcn_s_setprio(1);
#pragma unroll
    for (int t = 0; t < 4; t++) {
      half8 b[4];
#pragma unroll
      for (int c = 0; c < 4; c++)
        b[c] = *(const half8*)&lds.k[cur][(c * 4 + t) * 512 + lq];
#pragma unroll
      for (int c = 0; c < 4; c++)
        Sf[c] = __builtin_amdgcn_mfma_f32_16x16x32_f16(aq[t], b[c], Sf[c], 0, 0, 0);
    }
    __builtin_amdgcn_s_setprio(0);

    // ---- softmax (base-2): DPP row-max (VALU-only), exp2 ----
    float alpha[4];
    {
      float mt[4];
#pragma unroll
      for (int r = 0; r < 4; r++)
        mt[r] = fmaxf(fmaxf(Sf[0][r], Sf[1][r]), fmaxf(Sf[2][r], Sf[3][r]));
#pragma unroll
      for (int r = 0; r < 4; r++) mt[r] = dpp_max16(mt[r]);
#pragma unroll
      for (int r = 0; r < 4; r++) {
        const float mn = fmaxf(m_run[r], mt[r]);
        alpha[r] = __ocml_native_exp2_f32(m_run[r] - mn);
        m_run[r] = mn;
      }
#pragma unroll
      for (int r = 0; r < 4; r++)
#pragma unroll
        for (int c = 0; c < 4; c++)
          Sf[c][r] = __ocml_native_exp2_f32(Sf[c][r] - m_run[r]);
    }

    // ---- P: C-layout -> A-layout via wave-private frag-ordered LDS ----
#pragma unroll
    for (int c = 0; c < 4; c++)
#pragma unroll
      for (int r = 0; r < 4; r++)
        lds.p[wave][((c * 2 + (l4 >> 3)) * 16 + quad * 4 + r) * 8 + (l4 & 7)] =
            (_Float16)Sf[c][r];

    // ---- rescale O/l BEFORE V-loads (alpha dies before vfrag lives) ----
    {
      const bool moved = (alpha[0] != 1.f) | (alpha[1] != 1.f) |
                         (alpha[2] != 1.f) | (alpha[3] != 1.f);
      if (__any(moved)) {
#pragma unroll
        for (int c = 0; c < 8; c++) {
          Oacc[c][0] *= alpha[0]; Oacc[c][1] *= alpha[1];
          Oacc[c][2] *= alpha[2]; Oacc[c][3] *= alpha[3];
        }
        lacc[0] *= alpha[0]; lacc[1] *= alpha[1];
        lacc[2] *= alpha[2]; lacc[3] *= alpha[3];
      }
    }

    // ---- O += P@V, l += P@ones;  t-SPLIT: 8 V-frags (32 regs) at a time ----
#pragma unroll
    for (int t = 0; t < 2; t++) {
      half8 vf[8];
      {
        const _Float16* vtb = vfo_h + (size_t)kt * 8192 + t * 512 + lq;
#pragma unroll
        for (int c = 0; c < 8; c++)
          vf[c] = *(const half8*)(vtb + c * 1024);
      }
      half8 ap = *(const half8*)&lds.p[wave][((t * 4 + quad) * 16 + l4) * 8];
      __builtin_amdgcn_s_setprio(1);
      lacc = __builtin_amdgcn_mfma_f32_16x16x32_f16(ap, vones, lacc, 0, 0, 0);
#pragma unroll
      for (int c = 0; c < 8; c++)
        Oacc[c] = __builtin_amdgcn_mfma_f32_16x16x32_f16(ap, vf[c], Oacc[c], 0, 0, 0);
      __builtin_amdgcn_s_setprio(0);
    }
    // no trailing barrier: next iteration's barrier covers both hazards
  }

  // ---- epilogue: unnormalized partial O (fp16) + per-row (m, l) ----
  const int rbase = wave * 16 + quad * 4;
  const size_t rowbase = (size_t)(s * NHEAD + h) * NROWS + q0 + rbase;
#pragma unroll
  for (int c = 0; c < 8; c++) {
    const int col = c * 16 + l4;
#pragma unroll
    for (int r = 0; r < 4; r++)
      op[(rowbase + r) * DDIM + col] = (_Float16)Oacc[c][r];
  }
  if (l4 == 0) {
#pragma unroll
    for (int r = 0; r < 4; r++) {
      mb[rowbase + r] = m_run[r];
      lb[rowbase + r] = lacc[r];
    }
  }
}

// ---------------------------------------------------------------------------
// Kernel 3: merge 2 split-K partials + head-sum -> u. grid 4096, block 128.
// m values are in base-2 units -> exp2 here.
// ---------------------------------------------------------------------------
__global__ __launch_bounds__(128) void merge_kernel(
    const _Float16* __restrict__ op, const float* __restrict__ mb,
    const float* __restrict__ lb, const float* __restrict__ Wm,
    float* __restrict__ u)
{
  __shared__ float sc[2][NHEAD];
  const int n = blockIdx.x, d = threadIdx.x;
  if (d < NHEAD) {
    const int h = d;
    const float m1 = mb[(size_t)h * NROWS + n];
    const float m2 = mb[(size_t)(NHEAD + h) * NROWS + n];
    const float l1 = lb[(size_t)h * NROWS + n];
    const float l2 = lb[(size_t)(NHEAD + h) * NROWS + n];
    const float m  = fmaxf(m1, m2);
    const float a1 = __ocml_native_exp2_f32(m1 - m);
    const float a2 = __ocml_native_exp2_f32(m2 - m);
    const float invL = Wm[h] / (l1 * a1 + l2 * a2);
    sc[0][h] = a1 * invL;
    sc[1][h] = a2 * invL;
  }
  __syncthreads();
  float acc = 0.f;
#pragma unroll
  for (int h = 0; h < NHEAD; h++) {
    acc += sc[0][h] * (float)op[((size_t)h * NROWS + n) * DDIM + d];
    acc += sc[1][h] * (float)op[((size_t)(NHEAD + h) * NROWS + n) * DDIM + d];
  }
  u[(size_t)n * DDIM + d] = acc;
}

// ---------------------------------------------------------------------------
// Kernel 4: y = x + relu((x+u) @ Wg^T + bg), 3-term bf16 MFMA.
// Wg pre-split: staged via global_load_lds (no VALU).  grid 64, block 256.
// ---------------------------------------------------------------------------
__global__ __launch_bounds__(256, 2) void mlp_kernel(
    const float* __restrict__ x, const float* __restrict__ u,
    const unsigned short* __restrict__ wgpre, const float* __restrict__ bg,
    float* __restrict__ out)
{
  __shared__ alignas(16) unsigned short whi[8192];
  __shared__ alignas(16) unsigned short wlo[8192];
  const int tid = threadIdx.x, lane = tid & 63, wave = tid >> 6;
  const int l4 = lane & 15, quad = lane >> 4;
  const int r0 = blockIdx.x * 64;

  floatx4 acc[8];
#pragma unroll
  for (int c = 0; c < 8; c++) acc[c] = (floatx4)0.f;

  for (int fh = 0; fh < 2; fh++) {
    {
      const unsigned short* src = wgpre + fh * 16384;
      const unsigned short* sh = src + wave * 2048 + lane * 8;
      const unsigned short* sl = src + 8192 + wave * 2048 + lane * 8;
      unsigned short* dh = &whi[wave * 2048];
      unsigned short* dl = &wlo[wave * 2048];
#pragma unroll
      for (int it = 0; it < 4; it++) {
        async_cp16(sh + it * 512, dh + it * 512);
        async_cp16(sl + it * 512, dl + it * 512);
      }
    }
    __syncthreads();

    const size_t xoff = (size_t)(r0 + wave * 16 + l4) * DDIM + fh * 64 + quad * 8;
    short8 ah[2], al[2];
#pragma unroll
    for (int t2 = 0; t2 < 2; t2++) {
      float4 x0 = *(const float4*)(x + xoff + t2 * 32);
      float4 x1 = *(const float4*)(x + xoff + t2 * 32 + 4);
      float4 u0 = *(const float4*)(u + xoff + t2 * 32);
      float4 u1 = *(const float4*)(u + xoff + t2 * 32 + 4);
      float hv[8] = {x0.x + u0.x, x0.y + u0.y, x0.z + u0.z, x0.w + u0.w,
                     x1.x + u1.x, x1.y + u1.y, x1.z + u1.z, x1.w + u1.w};
#pragma unroll
      for (int j = 0; j < 8; j++) {
        unsigned short hi, lo; split2(hv[j], hi, lo);
        ah[t2][j] = (short)hi; al[t2][j] = (short)lo;
      }
    }
#pragma unroll
    for (int t2 = 0; t2 < 2; t2++) {
#pragma unroll
      for (int c = 0; c < 8; c++) {
        const int col = c * 16 + l4;
        const int idx = (col * 8 + ((t2 * 4 + quad) ^ (col & 7))) * 8;
        short8 bh = *(const short8*)&whi[idx];
        short8 bl = *(const short8*)&wlo[idx];
        acc[c] = __builtin_amdgcn_mfma_f32_16x16x32_bf16(ah[t2], bh, acc[c], 0, 0, 0);
        acc[c] = __builtin_amdgcn_mfma_f32_16x16x32_bf16(al[t2], bh, acc[c], 0, 0, 0);
        acc[c] = __builtin_amdgcn_mfma_f32_16x16x32_bf16(ah[t2], bl, acc[c], 0, 0, 0);
      }
    }
    __syncthreads();
  }

  const int rbase = wave * 16 + quad * 4;
#pragma unroll
  for (int c = 0; c < 8; c++) {
    const int col = c * 16 + l4;
    const float bgf = bg[col];
#pragma unroll
    for (int r = 0; r < 4; r++) {
      const size_t idx = (size_t)(r0 + rbase + r) * DDIM + col;
      out[idx] = x[idx] + fmaxf(acc[c][r] + bgf, 0.f);
    }
  }
}

extern "C" void kernel_launch(void* const* d_in, const int* in_sizes, int n_in,
                              void* d_out, int out_size, void* d_ws, size_t ws_size,
                              hipStream_t stream) {
  float* out = (float*)d_out;
  const int fill_blocks = (out_size + 255) / 256;

  const bool ok_sizes =
      n_in == 7 &&
      in_sizes[0] == NROWS * DDIM &&
      in_sizes[1] == NHEAD * DDIM * DDIM &&
      in_sizes[2] == NHEAD * DDIM * DDIM &&
      in_sizes[3] == NHEAD * DDIM * DDIM &&
      in_sizes[4] == NHEAD &&
      in_sizes[5] == DDIM * DDIM &&
      in_sizes[6] == DDIM &&
      out_size == NROWS * DDIM;
  if (!ok_sizes) {
    fill_kernel<<<fill_blocks, 256, 0, stream>>>(out, 1000.f, out_size);
    return;
  }

  // ws: u 2MB + k/v/qfo 25.2 + op(2) 16.8 + mb/lb 0.5 + wpre 1.5 + wgpre 0.06
  //     + xh/xl 2.1  = ~48 MB
  const size_t HND = (size_t)NHEAD * NROWS * DDIM;
  const size_t ND  = (size_t)NROWS * DDIM;
  const size_t WPRE_N  = (size_t)3 * 8 * 2 * 16384;  // ushorts
  const size_t WGPRE_N = (size_t)2 * 16384;
  const size_t need = ND * 4 + 3 * HND * 2 + 2 * HND * 2 +
                      2 * (2 * (size_t)NHEAD * NROWS) * 4 +
                      (WPRE_N + WGPRE_N + 2 * ND) * 2;
  if (ws_size < need) {
    fill_kernel<<<fill_blocks, 256, 0, stream>>>(out, 500.f, out_size);
    return;
  }

  const float* x  = (const float*)d_in[0];
  const float* Wk = (const float*)d_in[1];
  const float* Wq = (const float*)d_in[2];
  const float* Wv = (const float*)d_in[3];
  const float* Wm = (const float*)d_in[4];
  const float* Wg = (const float*)d_in[5];
  const float* bg = (const float*)d_in[6];

  float*          u     = (float*)d_ws;
  _Float16*       kfo   = (_Float16*)(u + ND);
  _Float16*       vfo   = kfo + HND;
  _Float16*       qfo   = vfo + HND;
  _Float16*       op    = qfo + HND;                 // 2*HND
  float*          mb    = (float*)(op + 2 * HND);    // 2*NHEAD*NROWS
  float*          lb    = mb + 2 * NHEAD * NROWS;
  unsigned short* wpre  = (unsigned short*)(lb + 2 * NHEAD * NROWS);
  unsigned short* wgpre = wpre + WPRE_N;
  unsigned short* xh    = wgpre + WGPRE_N;
  unsigned short* xl    = xh + ND;

  (void)hipGetLastError();
  prep_kernel<<<dim3(456), 256, 0, stream>>>(Wk, Wv, Wq, Wg, x, wpre, wgpre, xh, xl);
  proj_kernel<<<dim3(16, NHEAD, 3), 256, 0, stream>>>(xh, xl, wpre, kfo, vfo, qfo);
  flash_kernel<<<dim3(1024), 256, 0, stream>>>(qfo, kfo, vfo, op, mb, lb);
  merge_kernel<<<dim3(4096), 128, 0, stream>>>(op, mb, lb, Wm, u);
  mlp_kernel<<<dim3(64), 256, 0, stream>>>(x, u, wgpre, bg, out);
  if (hipGetLastError() != hipSuccess) {
    fill_kernel<<<fill_blocks, 256, 0, stream>>>(out, 2000.f, out_size);
  }
}